// Round 2
// baseline (296.297 us; speedup 1.0000x reference)
//
#include <hip/hip_runtime.h>
#include <hip/hip_bf16.h>

typedef unsigned int u32;
typedef unsigned short u16;
typedef __bf16 bf16x8 __attribute__((ext_vector_type(8)));
typedef float f32x4 __attribute__((ext_vector_type(4)));

// ---------- bf16 bit helpers ----------
__device__ __forceinline__ float b2f(u16 s){ union{u32 x; float f;} c; c.x = ((u32)s) << 16; return c.f; }
__device__ __forceinline__ float b2f_lo(u32 u){ union{u32 x; float f;} c; c.x = u << 16; return c.f; }
__device__ __forceinline__ float b2f_hi(u32 u){ union{u32 x; float f;} c; c.x = u & 0xFFFF0000u; return c.f; }
__device__ __forceinline__ u16 f2b(float f){
    union{float f; u32 u;} c; c.f = f;
    u32 r = c.u + 0x7FFFu + ((c.u >> 16) & 1u);
    return (u16)(r >> 16);
}
__device__ __forceinline__ u32 pk(float lo, float hi){
    return (u32)f2b(lo) | ((u32)f2b(hi) << 16);
}
// async global->LDS, 16B per lane (HW: wave-uniform base + lane*16)
__device__ __forceinline__ void gl_lds16(const u16* g, u16* l){
    __builtin_amdgcn_global_load_lds(
        (const __attribute__((address_space(1))) void*)g,
        (__attribute__((address_space(3))) void*)l, 16, 0, 0);
}
#define BARRIER() do { __builtin_amdgcn_s_barrier(); asm volatile("" ::: "memory"); } while(0)
#define SCB __builtin_amdgcn_sched_barrier(0)
#define PHASE_GATE() do { asm volatile("" ::: "memory"); __builtin_amdgcn_s_barrier(); \
    asm volatile("s_waitcnt lgkmcnt(0)" ::: "memory"); SCB; } while(0)
#define PHASE_END() do { SCB; __builtin_amdgcn_s_barrier(); asm volatile("" ::: "memory"); } while(0)
#define LD8(p) (*reinterpret_cast<const bf16x8*>(p))
// quad (MO..MO+3, NO..NO+1) over K=64 (both k-halves): 16 MFMA
#define QUAD(AF, BF, MO, NO) do { \
    _Pragma("unroll") \
    for (int mt = 0; mt < 4; ++mt){ \
      _Pragma("unroll") \
      for (int nt = 0; nt < 2; ++nt){ \
        acc[(MO)+mt][(NO)+nt] = __builtin_amdgcn_mfma_f32_16x16x32_bf16(AF[mt][0], BF[nt][0], acc[(MO)+mt][(NO)+nt], 0,0,0); \
        acc[(MO)+mt][(NO)+nt] = __builtin_amdgcn_mfma_f32_16x16x32_bf16(AF[mt][1], BF[nt][1], acc[(MO)+mt][(NO)+nt], 0,0,0); \
      } } } while(0)

// Problem constants: B=4, T=2048, D=1024, H=16, HD=64, NF=128, chunk C=128, NC=16
// All inputs FLOAT32; OUTPUT is FLOAT32.

// ---------- fp32 -> bf16 bulk convert (x) ----------
__global__ __launch_bounds__(256) void tobf16(const float* __restrict__ in, u16* __restrict__ out)
{
    size_t i = ((size_t)blockIdx.x * 256 + threadIdx.x) * 8;
    float4 a = *reinterpret_cast<const float4*>(in + i);
    float4 b = *reinterpret_cast<const float4*>(in + i + 4);
    uint4 v; v.x = pk(a.x, a.y); v.y = pk(a.z, a.w); v.z = pk(b.x, b.y); v.w = pk(b.z, b.w);
    *reinterpret_cast<uint4*>(out + i) = v;
}

// ---------- all 4 weight transposes (+fp32->bf16) in one dispatch ----------
__global__ __launch_bounds__(256) void transpose_all(const float* __restrict__ Wq, const float* __restrict__ Wk,
                                                     const float* __restrict__ Wv, const float* __restrict__ Wo,
                                                     u16* __restrict__ WTqkv, u16* __restrict__ WTo)
{
    const float* in; u16* out;
    switch (blockIdx.z){
        case 0:  in = Wq; out = WTqkv;           break;
        case 1:  in = Wk; out = WTqkv + 1048576; break;
        case 2:  in = Wv; out = WTqkv + 2097152; break;
        default: in = Wo; out = WTo;             break;
    }
    __shared__ u16 tile[64][72];
    int kb = blockIdx.x * 64, nb = blockIdx.y * 64, tid = threadIdx.x;
#pragma unroll
    for (int i = 0; i < 2; i++){
        int idx = tid + 256*i; int r = idx >> 3; int c8 = (idx & 7) * 8;
        const float* p = &in[(size_t)(kb + r)*1024 + nb + c8];
        float4 lo = *reinterpret_cast<const float4*>(p);
        float4 hi = *reinterpret_cast<const float4*>(p + 4);
        uint4 v;
        v.x = pk(lo.x, lo.y); v.y = pk(lo.z, lo.w);
        v.z = pk(hi.x, hi.y); v.w = pk(hi.z, hi.w);
        *reinterpret_cast<uint4*>(&tile[r][c8]) = v;
    }
    __syncthreads();
#pragma unroll
    for (int i = 0; i < 2; i++){
        int idx = tid + 256*i; int c = idx >> 3; int r8 = (idx & 7) * 8;
        u32 w[4];
#pragma unroll
        for (int j = 0; j < 4; j++)
            w[j] = (u32)tile[r8 + 2*j][c] | ((u32)tile[r8 + 2*j + 1][c] << 16);
        uint4 v; v.x = w[0]; v.y = w[1]; v.z = w[2]; v.w = w[3];
        *reinterpret_cast<uint4*>(&out[(size_t)(nb + c)*1024 + kb + r8]) = v;
    }
}

// ---------- m201-geometry 8-phase GEMM: tile 256x256, BK=64, 8 waves (2Mx4N), per-wave 128x64 ----------
// C[8192,N] = A[8192,1024]*W, BT = W^T (N x 1024). MODE 3: N=3072, bf16 remapped QKV out, grid (32,12).
// LDS 128KB: 2 bufs x 64KB { A0[0,8192) A1[8192,16384) B0[16384,24576) B1[24576,32768) } (u16 units).
// Per iter i: phases P1-4 compute K-tile 2i (buf0), P5-8 tile 2i+1 (buf1); each phase = one C-quadrant
// (64x32) x K=64 = 16 MFMA. Reads: P1: A-mh0(8)+B-nh0(4); P2: B-nh1(4); P3: A-mh1(8); P4: none (mirror P5-8).
// Stages (1-2 half-tiles/phase into region freed one phase earlier): P1: b1.A1(t2i+1); P3: b0.B0(t2i+2);
// P4: b0.B1+b0.A0; P5: b0.A1; P7: b1.B0(t2i+3); P8: b1.B1+b1.A0. vmcnt(6) at P4/P8 retires exactly the
// next-read tile, leaving 3 half-tiles (6 issues) in flight. Tail iter: vmcnt(0), stages predicated off.
// Swizzle (T2): lds[row*64 + (col ^ ((row&7)<<3))]; staged linear-dest with inverse-swizzled global col.
template<int MODE>
__global__ __launch_bounds__(512, 2) void gemm_256(const u16* __restrict__ A, const u16* __restrict__ BT,
                                                   float* __restrict__ outf, u16* __restrict__ outh)
{
    __shared__ u16 lds[2][32768];
    const int tid = threadIdx.x;
    const int l = tid & 63, w = tid >> 6;
    const int wr = w >> 2, wc = w & 3;          // 2M x 4N wave grid
    const int fr = l & 15, q = l >> 4;
    const int m0 = blockIdx.x * 256, n0 = blockIdx.y * 256;

    // staging: thread covers row (half*128 + (tid>>3) + i2*64), 16B at inverse-swizzled col
    const int srow = tid >> 3;
    const int scol = ((tid & 7) ^ (srow & 7)) << 3;
    const u16* Ag = A  + (size_t)(m0 + srow) * 1024 + scol;
    const u16* Bg = BT + (size_t)(n0 + srow) * 1024 + scol;
    const int sd = tid * 8;

    // fragment read offsets (u16): row local = {m/n sel}*16 + fr, row&7 == fr&7
    const int colk0 = (q*8)      ^ ((fr & 7) << 3);
    const int colk1 = (32 + q*8) ^ ((fr & 7) << 3);
    const int aoff = wr*8192 + fr*64;                              // wave's A block-half = wr
    const int boff = 16384 + (wc >> 1)*8192 + ((wc & 1)*64 + fr)*64;

    f32x4 acc[8][4] = {};
    bf16x8 af[4][2], bf0[2][2], bf1[2][2];

    auto stgA = [&](int buf, int half, int kt){
#pragma unroll
        for (int i2 = 0; i2 < 2; ++i2)
            gl_lds16(Ag + (size_t)(half*128 + i2*64)*1024 + kt*64,
                     &lds[buf][half*8192 + i2*4096 + sd]);
    };
    auto stgB = [&](int buf, int half, int kt){
#pragma unroll
        for (int i2 = 0; i2 < 2; ++i2)
            gl_lds16(Bg + (size_t)(half*128 + i2*64)*1024 + kt*64,
                     &lds[buf][16384 + half*8192 + i2*4096 + sd]);
    };

    // prologue: tile0 full (8 issues), tile1 B0,B1,A0 (6 issues); retire tile0
    stgA(0, 0, 0); stgA(0, 1, 0); stgB(0, 0, 0); stgB(0, 1, 0);
    stgB(1, 0, 1); stgB(1, 1, 1); stgA(1, 0, 1);
    asm volatile("s_waitcnt vmcnt(6)" ::: "memory");
    SCB;
    BARRIER();

    for (int i = 0; i < 8; ++i){
        const bool s = (i < 7);
        const int kE = 2*i + 2, kO = 2*i + 3;
        u16* L0 = &lds[0][0];
        u16* L1 = &lds[1][0];

        // ---- P1: even quad(0,0); read A-mh0 + B-nh0; stage b1.A1 (tile 2i+1) ----
#pragma unroll
        for (int mt = 0; mt < 4; ++mt){
            af[mt][0] = LD8(L0 + aoff + mt*1024 + colk0);
            af[mt][1] = LD8(L0 + aoff + mt*1024 + colk1);
        }
#pragma unroll
        for (int nt = 0; nt < 2; ++nt){
            bf0[nt][0] = LD8(L0 + boff + nt*1024 + colk0);
            bf0[nt][1] = LD8(L0 + boff + nt*1024 + colk1);
        }
        stgA(1, 1, 2*i + 1);
        PHASE_GATE();
        __builtin_amdgcn_s_setprio(1); QUAD(af, bf0, 0, 0); __builtin_amdgcn_s_setprio(0);
        PHASE_END();

        // ---- P2: even quad(0,1); read B-nh1 ----
#pragma unroll
        for (int nt = 0; nt < 2; ++nt){
            bf1[nt][0] = LD8(L0 + boff + (2+nt)*1024 + colk0);
            bf1[nt][1] = LD8(L0 + boff + (2+nt)*1024 + colk1);
        }
        PHASE_GATE();
        __builtin_amdgcn_s_setprio(1); QUAD(af, bf1, 0, 2); __builtin_amdgcn_s_setprio(0);
        PHASE_END();

        // ---- P3: even quad(1,0); read A-mh1; stage b0.B0 (tile 2i+2) ----
#pragma unroll
        for (int mt = 0; mt < 4; ++mt){
            af[mt][0] = LD8(L0 + aoff + 4096 + mt*1024 + colk0);
            af[mt][1] = LD8(L0 + aoff + 4096 + mt*1024 + colk1);
        }
        if (s) stgB(0, 0, kE);
        PHASE_GATE();
        __builtin_amdgcn_s_setprio(1); QUAD(af, bf0, 4, 0); __builtin_amdgcn_s_setprio(0);
        PHASE_END();

        // ---- P4: even quad(1,1); stage b0.B1+b0.A0; vmcnt gate for odd tile ----
        if (s){ stgB(0, 1, kE); stgA(0, 0, kE); }
        PHASE_GATE();
        __builtin_amdgcn_s_setprio(1); QUAD(af, bf1, 4, 2); __builtin_amdgcn_s_setprio(0);
        SCB;
        if (s) asm volatile("s_waitcnt vmcnt(6)" ::: "memory");
        else   asm volatile("s_waitcnt vmcnt(0)" ::: "memory");
        SCB;
        __builtin_amdgcn_s_barrier();
        asm volatile("" ::: "memory");

        // ---- P5: odd quad(0,0); read A-mh0 + B-nh0 (buf1); stage b0.A1 (tile 2i+2) ----
#pragma unroll
        for (int mt = 0; mt < 4; ++mt){
            af[mt][0] = LD8(L1 + aoff + mt*1024 + colk0);
            af[mt][1] = LD8(L1 + aoff + mt*1024 + colk1);
        }
#pragma unroll
        for (int nt = 0; nt < 2; ++nt){
            bf0[nt][0] = LD8(L1 + boff + nt*1024 + colk0);
            bf0[nt][1] = LD8(L1 + boff + nt*1024 + colk1);
        }
        if (s) stgA(0, 1, kE);
        PHASE_GATE();
        __builtin_amdgcn_s_setprio(1); QUAD(af, bf0, 0, 0); __builtin_amdgcn_s_setprio(0);
        PHASE_END();

        // ---- P6: odd quad(0,1); read B-nh1 ----
#pragma unroll
        for (int nt = 0; nt < 2; ++nt){
            bf1[nt][0] = LD8(L1 + boff + (2+nt)*1024 + colk0);
            bf1[nt][1] = LD8(L1 + boff + (2+nt)*1024 + colk1);
        }
        PHASE_GATE();
        __builtin_amdgcn_s_setprio(1); QUAD(af, bf1, 0, 2); __builtin_amdgcn_s_setprio(0);
        PHASE_END();

        // ---- P7: odd quad(1,0); read A-mh1; stage b1.B0 (tile 2i+3) ----
#pragma unroll
        for (int mt = 0; mt < 4; ++mt){
            af[mt][0] = LD8(L1 + aoff + 4096 + mt*1024 + colk0);
            af[mt][1] = LD8(L1 + aoff + 4096 + mt*1024 + colk1);
        }
        if (s) stgB(1, 0, kO);
        PHASE_GATE();
        __builtin_amdgcn_s_setprio(1); QUAD(af, bf0, 4, 0); __builtin_amdgcn_s_setprio(0);
        PHASE_END();

        // ---- P8: odd quad(1,1); stage b1.B1+b1.A0; vmcnt gate for next even tile ----
        if (s){ stgB(1, 1, kO); stgA(1, 0, kO); }
        PHASE_GATE();
        __builtin_amdgcn_s_setprio(1); QUAD(af, bf1, 4, 2); __builtin_amdgcn_s_setprio(0);
        SCB;
        if (s) asm volatile("s_waitcnt vmcnt(6)" ::: "memory");
        else   asm volatile("s_waitcnt vmcnt(0)" ::: "memory");
        SCB;
        __builtin_amdgcn_s_barrier();
        asm volatile("" ::: "memory");
    }

    // epilogue: C/D layout col=lane&15 (N), row=(lane>>4)*4+r (M)
#pragma unroll
    for (int it = 0; it < 8; ++it){
        int row0 = m0 + wr*128 + it*16 + q*4;
#pragma unroll
        for (int j = 0; j < 4; ++j){
            int col = n0 + wc*64 + j*16 + fr;
#pragma unroll
            for (int r = 0; r < 4; ++r){
                float val = acc[it][j][r];
                int row = row0 + r;
                if (MODE == 2){
                    outf[(size_t)row*1024 + col] = val;
                } else {
                    int which = col >> 10, colw = col & 1023;
                    int h = colw >> 6, d = colw & 63;
                    int bb = row >> 11, tt = row & 2047;
                    outh[(size_t)which*8388608 + (((size_t)(bb*16 + h))*2048 + tt)*64 + d] = f2b(val);
                }
            }
        }
    }
}

// ---------- 4-phase counted-vmcnt GEMM, tile 256x128 (kept for out-proj: grid 32x8 = exactly 1 round) ----------
template<int MODE>
__global__ __launch_bounds__(512, 2) void gemm_8p(const u16* __restrict__ A, const u16* __restrict__ BT,
                                                  float* __restrict__ outf, u16* __restrict__ outh)
{
    constexpr int NT = 16;            // K/BK = 1024/64
    __shared__ u16 lds[2][24576];     // per buf: [0,16384)=A, [16384,24576)=B
    const int tid = threadIdx.x;
    const int w = tid >> 6, l = tid & 63;
    const int wr = w >> 1, wc = w & 1;
    const int fr = l & 15, q = l >> 4;
    const int m0 = blockIdx.x * 256, n0 = blockIdx.y * 128;

    const int srow = w*16 + (l >> 3);
    const int scol = ((l & 7) ^ (srow & 7)) << 3;
    const u16* Ag = A  + (size_t)(m0 + srow) * 1024 + scol;
    const u16* Bg = BT + (size_t)(n0 + srow) * 1024 + scol;
    const int sd = w*1024 + l*8;

    const int colk0 = (q*8)      ^ ((fr & 7) << 3);
    const int colk1 = (32 + q*8) ^ ((fr & 7) << 3);
    const int arow = (wr*64 + fr) * 64;
    const int brow = 16384 + (wc*64 + fr) * 64;

    f32x4 acc[4][4] = {};

#pragma unroll
    for (int kt = 0; kt < 2; ++kt){
        u16* Lb = lds[kt];
#pragma unroll
        for (int i = 0; i < 2; ++i){
            gl_lds16(Ag + (size_t)(i*8)*1024       + kt*64, Lb + sd + i*512);
            gl_lds16(Ag + (size_t)(128 + i*8)*1024 + kt*64, Lb + 8192 + sd + i*512);
            gl_lds16(Bg + (size_t)(i*8)*1024       + kt*64, Lb + 16384 + sd + i*512);
        }
    }
    asm volatile("s_waitcnt vmcnt(6)" ::: "memory");
    SCB;
    BARRIER();

    for (int t = 0; t < NT; ++t){
        u16* Lb = lds[t & 1];
        const int kt = t + 2;
        const bool st = (kt < NT);
        bf16x8 afv[4][2], bfr[4][2];

#pragma unroll
        for (int i = 0; i < 4; ++i){
            afv[i][0] = LD8(Lb + arow + i*1024 + colk0);
            afv[i][1] = LD8(Lb + arow + i*1024 + colk1);
        }
#pragma unroll
        for (int j = 0; j < 4; ++j)
            bfr[j][0] = LD8(Lb + brow + j*1024 + colk0);
        PHASE_GATE();
        __builtin_amdgcn_s_setprio(1);
#pragma unroll
        for (int i = 0; i < 2; ++i)
#pragma unroll
            for (int j = 0; j < 4; ++j)
                acc[i][j] = __builtin_amdgcn_mfma_f32_16x16x32_bf16(afv[i][0], bfr[j][0], acc[i][j], 0, 0, 0);
        __builtin_amdgcn_s_setprio(0);
        PHASE_END();

#pragma unroll
        for (int j = 0; j < 4; ++j)
            bfr[j][1] = LD8(Lb + brow + j*1024 + colk1);
        if (st){
#pragma unroll
            for (int i = 0; i < 2; ++i){
                gl_lds16(Ag + (size_t)(i*8)*1024       + kt*64, Lb + sd + i*512);
                gl_lds16(Ag + (size_t)(128 + i*8)*1024 + kt*64, Lb + 8192 + sd + i*512);
            }
        }
        PHASE_GATE();
        __builtin_amdgcn_s_setprio(1);
#pragma unroll
        for (int i = 2; i < 4; ++i)
#pragma unroll
            for (int j = 0; j < 4; ++j)
                acc[i][j] = __builtin_amdgcn_mfma_f32_16x16x32_bf16(afv[i][0], bfr[j][0], acc[i][j], 0, 0, 0);
        __builtin_amdgcn_s_setprio(0);
        PHASE_END();

        if (st){
#pragma unroll
            for (int i = 0; i < 2; ++i)
                gl_lds16(Bg + (size_t)(i*8)*1024 + kt*64, Lb + 16384 + sd + i*512);
        }
        __builtin_amdgcn_s_barrier();
        __builtin_amdgcn_s_setprio(1);
#pragma unroll
        for (int i = 0; i < 2; ++i)
#pragma unroll
            for (int j = 0; j < 4; ++j)
                acc[i][j] = __builtin_amdgcn_mfma_f32_16x16x32_bf16(afv[i][1], bfr[j][1], acc[i][j], 0, 0, 0);
        __builtin_amdgcn_s_setprio(0);
        PHASE_END();

        __builtin_amdgcn_s_setprio(1);
#pragma unroll
        for (int i = 2; i < 4; ++i)
#pragma unroll
            for (int j = 0; j < 4; ++j)
                acc[i][j] = __builtin_amdgcn_mfma_f32_16x16x32_bf16(afv[i][1], bfr[j][1], acc[i][j], 0, 0, 0);
        __builtin_amdgcn_s_setprio(0);
        SCB;
        if (t < NT - 2)
            asm volatile("s_waitcnt vmcnt(6)" ::: "memory");
        else
            asm volatile("s_waitcnt vmcnt(0)" ::: "memory");
        SCB;
        BARRIER();
    }

#pragma unroll
    for (int i = 0; i < 4; i++){
        int row0 = m0 + wr*64 + i*16 + q*4;
#pragma unroll
        for (int j = 0; j < 4; j++){
            int col = n0 + wc*64 + j*16 + fr;
#pragma unroll
            for (int r = 0; r < 4; r++){
                float val = acc[i][j][r];
                int row = row0 + r;
                if (MODE == 2){
                    outf[(size_t)row*1024 + col] = val;
                } else {
                    int which = col >> 10, colw = col & 1023;
                    int h = colw >> 6, d = colw & 63;
                    int bb = row >> 11, tt = row & 2047;
                    outh[(size_t)which*8388608 + (((size_t)(bb*16 + h))*2048 + tt)*64 + d] = f2b(val);
                }
            }
        }
    }
}

// ---------- FAVOR+ feature map via MFMA (q path): phi = exp(x.Wf - 0.5||x||^2)/sqrt(NF) ----------
__global__ __launch_bounds__(256) void featmap_mfma(const u16* __restrict__ xh, const float* __restrict__ Wf,
                                                    u16* __restrict__ xp)
{
    __shared__ u16 Xl[128][72];
    __shared__ u16 Wft[128][72];
    __shared__ float sqp[128][8];
    __shared__ float sql[128];
    int tid = threadIdx.x;
    int lane = tid & 63, w = tid >> 6;
    int m = lane & 15, q = lane >> 4;
    const u16* xb = xh + (size_t)blockIdx.x * 128 * 64;
#pragma unroll
    for (int it = 0; it < 4; it++){
        int idx = tid + 256*it;
        int row = idx >> 3, c8 = (idx & 7) * 8;
        uint4 v = *reinterpret_cast<const uint4*>(xb + (size_t)row*64 + c8);
        *reinterpret_cast<uint4*>(&Xl[row][c8]) = v;
        u32 ww[4] = {v.x, v.y, v.z, v.w};
        float s = 0.f;
#pragma unroll
        for (int j = 0; j < 4; j++){
            float a = b2f_lo(ww[j]), bb = b2f_hi(ww[j]);
            s += a*a + bb*bb;
        }
        sqp[row][idx & 7] = s;
    }
#pragma unroll
    for (int it = 0; it < 8; it++){
        int idx = tid + 256*it;
        int d = idx >> 5, f4 = (idx & 31) * 4;
        float4 v = *reinterpret_cast<const float4*>(Wf + d*128 + f4);
        Wft[f4+0][d] = f2b(v.x); Wft[f4+1][d] = f2b(v.y);
        Wft[f4+2][d] = f2b(v.z); Wft[f4+3][d] = f2b(v.w);
    }
    __syncthreads();
    if (tid < 128){
        float s = 0.f;
#pragma unroll
        for (int j = 0; j < 8; j++) s += sqp[tid][j];
        sql[tid] = s;
    }
    f32x4 acc[2][8] = {};
#pragma unroll
    for (int ks = 0; ks < 2; ks++){
        bf16x8 af[2], bf[8];
#pragma unroll
        for (int mt = 0; mt < 2; mt++)
            af[mt] = *reinterpret_cast<const bf16x8*>(&Xl[32*w + mt*16 + m][ks*32 + q*8]);
#pragma unroll
        for (int nt = 0; nt < 8; nt++)
            bf[nt] = *reinterpret_cast<const bf16x8*>(&Wft[nt*16 + m][ks*32 + q*8]);
#pragma unroll
        for (int mt = 0; mt < 2; mt++)
#pragma unroll
            for (int nt = 0; nt < 8; nt++)
                acc[mt][nt] = __builtin_amdgcn_mfma_f32_16x16x32_bf16(af[mt], bf[nt], acc[mt][nt], 0, 0, 0);
    }
    __syncthreads();
    const float c = 0.08838834764831845f; // 1/sqrt(128)
    u16* xpb = xp + (size_t)blockIdx.x * 128 * 128;
#pragma unroll
    for (int mt = 0; mt < 2; mt++){
#pragma unroll
        for (int r = 0; r < 4; r++){
            int t = 32*w + mt*16 + q*4 + r;
            float hs = 0.5f * sql[t];
#pragma unroll
            for (int nt = 0; nt < 8; nt++){
                int f = nt*16 + m;
                xpb[(size_t)t*128 + f] = f2b(__expf(fminf(acc[mt][nt][r] - hs, 60.f)) * c);
            }
        }
    }
}

// ---------- k path: featmap + per-chunk KV summary fused ----------
// One block = one (bh, chunk): computes kp = phi(k), S^T[d][f] = V^T.kp (MFMA), z = colsum(kp).
struct FM1 { u16 Xl[128][72]; u16 Wft[128][72]; };
union  FMU { FM1 p1; u16 Kpt[128][136]; };
__global__ __launch_bounds__(256) void featmap_sum(const u16* __restrict__ kh, const float* __restrict__ Wf,
                                                   const u16* __restrict__ vh, u16* __restrict__ kp,
                                                   u16* __restrict__ Sa, float* __restrict__ zs)
{
    __shared__ FMU sm;
    __shared__ u16 Vt[64][136];
    __shared__ float sqp[128][8];
    __shared__ float sql[128];
    int blk = blockIdx.x, tid = threadIdx.x;
    int lane = tid & 63, w = tid >> 6;
    int m = lane & 15, q = lane >> 4;
    const u16* xb = kh + (size_t)blk * 128 * 64;
    const u16* vb = vh + (size_t)blk * 128 * 64;   // same (bh,chunk) flat layout
    // stage K-chunk + sq partials
#pragma unroll
    for (int it = 0; it < 4; it++){
        int idx = tid + 256*it;
        int row = idx >> 3, c8 = (idx & 7) * 8;
        uint4 v = *reinterpret_cast<const uint4*>(xb + (size_t)row*64 + c8);
        *reinterpret_cast<uint4*>(&sm.p1.Xl[row][c8]) = v;
        u32 ww[4] = {v.x, v.y, v.z, v.w};
        float s = 0.f;
#pragma unroll
        for (int j = 0; j < 4; j++){
            float a = b2f_lo(ww[j]), bb = b2f_hi(ww[j]);
            s += a*a + bb*bb;
        }
        sqp[row][idx & 7] = s;
    }
    // stage Wf^T
#pragma unroll
    for (int it = 0; it < 8; it++){
        int idx = tid + 256*it;
        int d = idx >> 5, f4 = (idx & 31) * 4;
        float4 v = *reinterpret_cast<const float4*>(Wf + d*128 + f4);
        sm.p1.Wft[f4+0][d] = f2b(v.x); sm.p1.Wft[f4+1][d] = f2b(v.y);
        sm.p1.Wft[f4+2][d] = f2b(v.z); sm.p1.Wft[f4+3][d] = f2b(v.w);
    }
    // stage V transposed
#pragma unroll
    for (int it = 0; it < 4; it++){
        int idx = tid + 256*it;
        int t = idx >> 3, d8 = (idx & 7)*8;
        uint4 v = *reinterpret_cast<const uint4*>(vb + (size_t)t*64 + d8);
        u32 ww[4] = {v.x, v.y, v.z, v.w};
#pragma unroll
        for (int j = 0; j < 4; j++){
            Vt[d8 + 2*j][t]     = (u16)(ww[j] & 0xFFFFu);
            Vt[d8 + 2*j + 1][t] = (u16)(ww[j] >> 16);
        }
    }
    __syncthreads();
    if (tid < 128){
        float s = 0.f;
#pragma unroll
        for (int j = 0; j < 8; j++) s += sqp[tid][j];
        sql[tid] = s;
    }
    // phi MFMA
    f32x4 acc[2][8] = {};
#pragma unroll
    for (int ks = 0; ks < 2; ks++){
        bf16x8 af[2], bf[8];
#pragma unroll
        for (int mt = 0; mt < 2; mt++)
            af[mt] = *reinterpret_cast<const bf16x8*>(&sm.p1.Xl[32*w + mt*16 + m][ks*32 + q*8]);
#pragma unroll
        for (int nt = 0; nt < 8; nt++)
            bf[nt] = *reinterpret_cast<const bf16x8*>(&sm.p1.Wft[nt*16 + m][ks*32 + q*8]);
#pragma unroll
        for (int mt = 0; mt < 2; mt++)
#pragma unroll
            for (int nt = 0; nt < 8; nt++)
                acc[mt][nt] = __builtin_amdgcn_mfma_f32_16x16x32_bf16(af[mt], bf[nt], acc[mt][nt], 0, 0, 0);
    }
    __syncthreads();   // Xl/Wft reads complete (region about to be overwritten), sql visible
    // epilogue: phi -> global kp AND transposed LDS Kpt[f][t]
    const float c = 0.08838834764831845f;
    u16* xpb = kp + (size_t)blk * 128 * 128;
#pragma unroll
    for (int mt = 0; mt < 2; mt++){
#pragma unroll
        for (int r = 0; r < 4; r++){
            int t = 32*w + mt*16 + q*4 + r;
            float hs = 0.5f * sql[t];
#pragma unroll
            for (int nt = 0; nt < 8; nt++){
                int f = nt*16 + m;
                u16 pv = f2b(__expf(fminf(acc[mt][nt][r] - hs, 60.f)) * c);
                xpb[(size_t)t*128 + f] = pv;
                sm.Kpt[f][t] = pv;
            }
        }
    }
    __syncthreads();   // Kpt ready
    // S^T = V^T . kp : A[d][t]=Vt, B[f][t]=Kpt ; wave w -> d rows [16w,16w+16)
    f32x4 acc2[8] = {};
#pragma unroll
    for (int ks = 0; ks < 4; ks++){
        bf16x8 af = *reinterpret_cast<const bf16x8*>(&Vt[16*w + m][ks*32 + q*8]);
        bf16x8 bf[8];
#pragma unroll
        for (int nt = 0; nt < 8; nt++)
            bf[nt] = *reinterpret_cast<const bf16x8*>(&sm.Kpt[nt*16 + m][ks*32 + q*8]);
#pragma unroll
        for (int nt = 0; nt < 8; nt++)
            acc2[nt] = __builtin_amdgcn_mfma_f32_16x16x32_bf16(af, bf[nt], acc2[nt], 0, 0, 0);
    }
    u16* Sb = Sa + (size_t)blk*8192;
#pragma unroll
    for (int nt = 0; nt < 8; nt++){
#pragma unroll
        for (int r = 0; r < 4; r++){
            int d = 16*w + q*4 + r;
            int f = nt*16 + m;
            Sb[(size_t)d*128 + f] = f2b(acc2[nt][r]);
        }
    }
    // z = colsum(kp) from Kpt rows (17-stride bank walk: 2-way, free)
    if (tid < 128){
        float z = 0.f;
#pragma unroll
        for (int t = 0; t < 128; t++) z += b2f(sm.Kpt[tid][t]);
        zs[(size_t)blk*128 + tid] = z;
    }
}

// ---------- exclusive prefix over the 16 chunks (per bh), bf16 in/out ----------
__global__ __launch_bounds__(256) void prefix_chunks(const u16* __restrict__ Sa, u16* __restrict__ Sb,
                                                     float* __restrict__ zs)
{
    int bh = blockIdx.x, seg = blockIdx.y, tid = threadIdx.x;
    const u16* src = Sa + (size_t)bh*16*8192;
    u16*       dst = Sb + (size_t)bh*16*8192;
#pragma unroll
    for (int it = 0; it < 4; it++){
        int e = seg*1024 + it*256 + tid;
        float run = 0.f;
#pragma unroll
        for (int c = 0; c < 16; c++){
            float v = b2f(src[(size_t)c*8192 + e]);
            dst[(size_t)c*8192 + e] = f2b(run);
            run += v;
        }
    }
    if (seg == 0 && tid < 128){
        float run = 0.f; float* zp = zs + (size_t)bh*16*128 + tid;
#pragma unroll
        for (int c = 0; c < 16; c++){ float v = zp[c*128]; zp[c*128] = run; run += v; }
    }
}

// ---------- per-chunk output via MFMA; denominator fused as extra MFMA B-tiles ----------
__global__ __launch_bounds__(256) void chunk_out(const u16* __restrict__ qp, const u16* __restrict__ kp,
                                                 const u16* __restrict__ vh, const u16* __restrict__ St,
                                                 const float* __restrict__ zs, u16* __restrict__ y2d)
{
    __shared__ u16 P[128][136];
    __shared__ u16 Vt[64][136];
    __shared__ u16 zl[128];
    int blk = blockIdx.x, tid = threadIdx.x;
    int lane = tid & 63, w = tid >> 6;
    int m = lane & 15, q = lane >> 4;
    int bh = blk >> 4, c = blk & 15;
    int b = bh >> 4, h = bh & 15, t0 = c*128;
    const u16* qpb = qp + ((size_t)bh*2048 + t0)*128;
    const u16* kpb = kp + ((size_t)bh*2048 + t0)*128;
    const u16* vb  = vh + ((size_t)bh*2048 + t0)*64;
    const u16* Stb = St + (size_t)blk*8192;

    if (tid < 128) zl[tid] = f2b(zs[(size_t)blk*128 + tid]);
#pragma unroll
    for (int it = 0; it < 4; it++){
        int idx = tid + 256*it;
        int t = idx >> 3, d8 = (idx & 7)*8;
        uint4 v = *reinterpret_cast<const uint4*>(&vb[(size_t)t*64 + d8]);
        u32 ww[4] = {v.x, v.y, v.z, v.w};
#pragma unroll
        for (int j = 0; j < 4; j++){
            Vt[d8 + 2*j][t]     = (u16)(ww[j] & 0xFFFFu);
            Vt[d8 + 2*j + 1][t] = (u16)(ww[j] >> 16);
        }
    }
    {
        int row = tid >> 1, half = tid & 1;
        int i = row >> 4;
        for (int s2 = 16*(i + 1) + half*2; s2 < 128; s2 += 4)
            *reinterpret_cast<u32*>(&P[row][s2]) = 0;
    }
    {
        static const unsigned char TIa[36] = {0,1,1,2,2,2,3,3,3,3,4,4,4,4,4,
                                              5,5,5,5,5,5,6,6,6,6,6,6,6,7,7,7,7,7,7,7,7};
        static const unsigned char TJa[36] = {0,0,1,0,1,2,0,1,2,3,0,1,2,3,4,
                                              0,1,2,3,4,5,0,1,2,3,4,5,6,0,1,2,3,4,5,6,7};
        for (int idx = w; idx < 36; idx += 4){
            int i = TIa[idx], j = TJa[idx];
            f32x4 a = {};
            const u16* arow = qpb + (size_t)(i*16 + m)*128 + q*8;
            const u16* brow = kpb + (size_t)(j*16 + m)*128 + q*8;
#pragma unroll
            for (int ks = 0; ks < 4; ks++){
                bf16x8 af = *reinterpret_cast<const bf16x8*>(arow + ks*32);
                bf16x8 bf = *reinterpret_cast<const bf16x8*>(brow + ks*32);
                a = __builtin_amdgcn_mfma_f32_16x16x32_bf16(af, bf, a, 0, 0, 0);
            }
            int scol = j*16 + m;
#pragma unroll
            for (int r = 0; r < 4; r++){
                int trow = i*16 + q*4 + r;
                P[trow][scol] = (scol <= trow) ? f2b(a[r]) : (u16)0;
            }
        }
    }
    __syncthreads();
    f32x4 acc[2][4] = {};
    f32x4 accd[2] = {};
    bf16x8 ones;
#pragma unroll
    for (int i = 0; i < 8; i++) ones[i] = (__bf16)1.0f;
    for (int ks = 0; ks <= w; ks++){
        bf16x8 af[2], bf4[4];
#pragma unroll
        for (int mt = 0; mt < 2; mt++)
            af[mt] = *reinterpret_cast<const bf16x8*>(&P[32*w + mt*16 + m][ks*32 + q*8]);
#pragma unroll
        for (int nt = 0; nt < 4; nt++)
            bf4[nt] = *reinterpret_cast<const bf16x8*>(&Vt[nt*16 + m][ks*32 + q*8]);
#pragma unroll
        for (int mt = 0; mt < 2; mt++){
#pragma unroll
            for (int nt = 0; nt < 4; nt++)
                acc[mt][nt] = __builtin_amdgcn_mfma_f32_16x16x32_bf16(af[mt], bf4[nt], acc[mt][nt], 0, 0, 0);
            accd[mt] = __builtin_amdgcn_mfma_f32_16x16x32_bf16(af[mt], ones, accd[mt], 0, 0, 0);
        }
    }
#pragma unroll
    for (int ks = 0; ks < 4; ks++){
        bf16x8 af[2], bf4[4];
        bf16x8 zf = *reinterpret_cast<const bf16x8*>(&zl[ks*32 + q*8]);
#pragma unroll
        for (int mt = 0; mt < 2; mt++)
            af[mt] = *reinterpret_cast<const bf16x8*>(qpb + (size_t)(32*w + mt*16 + m)*128 + ks*32 + q*8);
#pragma unroll
        for (int nt = 0; nt < 4; nt++)
            bf4[nt] = *reinterpret_cast<const bf16x8*>(Stb + (size_t)(nt*16 + m)*128 + ks*32 + q*8);
#pragma unroll
        for (int mt = 0; mt < 2; mt++){
#pragma unroll
            for (int nt = 0; nt < 4; nt++)
                acc[mt][nt] = __builtin_amdgcn_mfma_f32_16x16x32_bf16(af[mt], bf4[nt], acc[mt][nt], 0, 0, 0);
            accd[mt] = __builtin_amdgcn_mfma_f32_16x16x32_bf16(af[mt], zf, accd[mt], 0, 0, 0);
        }
    }
#pragma unroll
    for (int mt = 0; mt < 2; mt++){
#pragma unroll
        for (int nt = 0; nt < 4; nt++){
#pragma unroll
            for (int r = 0; r < 4; r++){
                int t = 32*w + mt*16 + q*4 + r;
                int d = nt*16 + m;
                float den = accd[mt][r] + 1e-6f;
                y2d[((size_t)b*2048 + t0 + t)*1024 + h*64 + d] = f2b(acc[mt][nt][r] / den);
            }
        }
    }
}

extern "C" void kernel_launch(void* const* d_in, const int* in_sizes, int n_in,
                              void* d_out, int out_size, void* d_ws, size_t ws_size,
                              hipStream_t stream)
{
    (void)in_sizes; (void)n_in; (void)out_size; (void)ws_size;
    const float* x  = (const float*)d_in[0];
    const float* Wq = (const float*)d_in[1];
    const float* Wk = (const float*)d_in[2];
    const float* Wv = (const float*)d_in[3];
    const float* Wo = (const float*)d_in[4];
    const float* Wf = (const float*)d_in[5];
    float* out = (float*)d_out;
    char* ws = (char*)d_ws;

    // workspace layout (lifetime-aliased, ~136.5 MiB)
    u16*   xh    = (u16*)  (ws + 0);           // 16MB x bf16 (dead after QKV gemm)
    u16*   Sa    = (u16*)  (ws + 0);           // alias xh: chunk S^T raw bf16
    u16*   qh    = (u16*)  (ws + 16777216);    // 16MB (dead after featmap q)
    u16*   Sbp   = (u16*)  (ws + 16777216);    // alias qh: prefix S^T
    u16*   kh    = (u16*)  (ws + 33554432);    // 16MB (dead after featmap_sum)
    u16*   y2d   = (u16*)  (ws + 33554432);    // alias kh
    u16*   vh    = (u16*)  (ws + 50331648);    // 16MB
    u16*   qp    = (u16*)  (ws + 67108864);    // 32MB
    u16*   kp    = (u16*)  (ws + 100663296);   // 32MB
    u16*   WTqkv = (u16*)  (ws + 134217728);   // 6MB (3 x 1024x1024 bf16)
    u16*   WTo   = (u16*)  (ws + 140509184);   // 2MB
    float* zs    = (float*)(ws + 142606336);   // 0.5MB

    tobf16<<<4096, 256, 0, stream>>>(x, xh);
    transpose_all<<<dim3(16, 16, 4), 256, 0, stream>>>(Wq, Wk, Wv, Wo, WTqkv, WTo);

    // fused QKV: writes qh, kh, vh (contiguous 16MB blocks starting at qh)
    gemm_256<3><<<dim3(32, 12), 512, 0, stream>>>(xh, WTqkv, nullptr, qh);

    featmap_mfma<<<1024, 256, 0, stream>>>(qh, Wf, qp);
    featmap_sum<<<1024, 256, 0, stream>>>(kh, Wf, vh, kp, Sa, zs);

    prefix_chunks<<<dim3(64, 8), 256, 0, stream>>>(Sa, Sbp, zs);
    chunk_out<<<1024, 256, 0, stream>>>(qp, kp, vh, Sbp, zs, y2d);

    gemm_8p<2><<<dim3(32, 8), 512, 0, stream>>>(y2d, WTo, out, nullptr);
}

// Round 3
// 292.937 us; speedup vs baseline: 1.0115x; 1.0115x over previous
//
#include <hip/hip_runtime.h>
#include <hip/hip_bf16.h>

typedef unsigned int u32;
typedef unsigned short u16;
typedef __bf16 bf16x8 __attribute__((ext_vector_type(8)));
typedef float f32x4 __attribute__((ext_vector_type(4)));

// ---------- bf16 bit helpers ----------
__device__ __forceinline__ float b2f(u16 s){ union{u32 x; float f;} c; c.x = ((u32)s) << 16; return c.f; }
__device__ __forceinline__ float b2f_lo(u32 u){ union{u32 x; float f;} c; c.x = u << 16; return c.f; }
__device__ __forceinline__ float b2f_hi(u32 u){ union{u32 x; float f;} c; c.x = u & 0xFFFF0000u; return c.f; }
__device__ __forceinline__ u16 f2b(float f){
    union{float f; u32 u;} c; c.f = f;
    u32 r = c.u + 0x7FFFu + ((c.u >> 16) & 1u);
    return (u16)(r >> 16);
}
__device__ __forceinline__ u32 pk(float lo, float hi){
    return (u32)f2b(lo) | ((u32)f2b(hi) << 16);
}
// async global->LDS, 16B per lane (HW: wave-uniform base + lane*16)
__device__ __forceinline__ void gl_lds16(const u16* g, u16* l){
    __builtin_amdgcn_global_load_lds(
        (const __attribute__((address_space(1))) void*)g,
        (__attribute__((address_space(3))) void*)l, 16, 0, 0);
}
#define BARRIER() do { __builtin_amdgcn_s_barrier(); asm volatile("" ::: "memory"); } while(0)
#define SCB __builtin_amdgcn_sched_barrier(0)
#define PHASE_GATE() do { asm volatile("" ::: "memory"); __builtin_amdgcn_s_barrier(); \
    asm volatile("s_waitcnt lgkmcnt(0)" ::: "memory"); SCB; } while(0)
#define LD8(p) (*reinterpret_cast<const bf16x8*>(p))

// Problem constants: B=4, T=2048, D=1024, H=16, HD=64, NF=128, chunk C=128, NC=16
// All inputs FLOAT32; OUTPUT is FLOAT32.

// ---------- fp32 -> bf16 bulk convert (x) ----------
__global__ __launch_bounds__(256) void tobf16(const float* __restrict__ in, u16* __restrict__ out)
{
    size_t i = ((size_t)blockIdx.x * 256 + threadIdx.x) * 8;
    float4 a = *reinterpret_cast<const float4*>(in + i);
    float4 b = *reinterpret_cast<const float4*>(in + i + 4);
    uint4 v; v.x = pk(a.x, a.y); v.y = pk(a.z, a.w); v.z = pk(b.x, b.y); v.w = pk(b.z, b.w);
    *reinterpret_cast<uint4*>(out + i) = v;
}

// ---------- all 4 weight transposes (+fp32->bf16) in one dispatch ----------
__global__ __launch_bounds__(256) void transpose_all(const float* __restrict__ Wq, const float* __restrict__ Wk,
                                                     const float* __restrict__ Wv, const float* __restrict__ Wo,
                                                     u16* __restrict__ WTqkv, u16* __restrict__ WTo)
{
    const float* in; u16* out;
    switch (blockIdx.z){
        case 0:  in = Wq; out = WTqkv;           break;
        case 1:  in = Wk; out = WTqkv + 1048576; break;
        case 2:  in = Wv; out = WTqkv + 2097152; break;
        default: in = Wo; out = WTo;             break;
    }
    __shared__ u16 tile[64][72];
    int kb = blockIdx.x * 64, nb = blockIdx.y * 64, tid = threadIdx.x;
#pragma unroll
    for (int i = 0; i < 2; i++){
        int idx = tid + 256*i; int r = idx >> 3; int c8 = (idx & 7) * 8;
        const float* p = &in[(size_t)(kb + r)*1024 + nb + c8];
        float4 lo = *reinterpret_cast<const float4*>(p);
        float4 hi = *reinterpret_cast<const float4*>(p + 4);
        uint4 v;
        v.x = pk(lo.x, lo.y); v.y = pk(lo.z, lo.w);
        v.z = pk(hi.x, hi.y); v.w = pk(hi.z, hi.w);
        *reinterpret_cast<uint4*>(&tile[r][c8]) = v;
    }
    __syncthreads();
#pragma unroll
    for (int i = 0; i < 2; i++){
        int idx = tid + 256*i; int c = idx >> 3; int r8 = (idx & 7) * 8;
        u32 w[4];
#pragma unroll
        for (int j = 0; j < 4; j++)
            w[j] = (u32)tile[r8 + 2*j][c] | ((u32)tile[r8 + 2*j + 1][c] << 16);
        uint4 v; v.x = w[0]; v.y = w[1]; v.z = w[2]; v.w = w[3];
        *reinterpret_cast<uint4*>(&out[(size_t)(nb + c)*1024 + kb + r8]) = v;
    }
}

// ---------- 2-phase/K-tile counted-vmcnt GEMM: tile 128x256, BK=64, 8 waves (2Mx4N), per-wave 64x64 ----------
// C[8192,N] = A[8192,1024]*W, BT = W^T (N x 1024 row-major).
// MODE 3: N=3072, bf16 remapped QKV out, grid (64,12) = 768 = EXACTLY 3 rounds of 256 CUs.
// MODE 2: N=1024, fp32 row-major out,  grid (64,4)  = 256 = EXACTLY 1 round.
// LDS 96KB: 2 bufs x 48KB { A[0,8192)=128x64 swz, B[8192,24576)=256x64 swz } (u16 units) -> 1 block/CU.
// Per K-tile (16 total): P1 reads af(8)+bf01(4), 16 MFMA (nt0-1); P2 reads bf23(4), 16 MFMA (nt2-3).
// Staging (region-lifetime-safe, one ENDBAR between a region's last-read gate and its overwrite):
//   P1(u): stage B(u+1) -> buf[(u+1)&1].B   [that region's reads finished at P2(u-1)'s gate]
//   P2(u): stage A(u+2) -> buf[u&1].A       [af(u) reads finished at P1(u)'s gate]
// Issue order ... B(u)@P1(u-1), A(u+1)@P2(u-1), B(u+1)@P1(u), A(u+2)@P2(u) ... so ONE s_waitcnt
// vmcnt(2) at end-P2(u) (newest-2 = A(u+2)) retires exactly tile u+1. Prologue {A0,B0,A1}+vmcnt(2).
// Tail: u=14 gates with vmcnt(0); stages predicated off for u+k > 15. Never vmcnt(0) mid-loop.
// Swizzle (T2): lds[row*64 + (col ^ ((row&7)<<3))]; linear global_load_lds dest + inverse-swizzled
// global source col; reads apply the same XOR. (Verified 0 bank conflicts in rounds 1-2.)
template<int MODE>
__global__ __launch_bounds__(512, 2) void gemm_2p(const u16* __restrict__ A, const u16* __restrict__ BT,
                                                  float* __restrict__ outf, u16* __restrict__ outh)
{
    __shared__ u16 lds[2][24576];
    const int tid = threadIdx.x;
    const int l = tid & 63, w = tid >> 6;
    const int wr = w >> 2, wc = w & 3;          // 2M x 4N wave grid, per-wave 64x64
    const int fr = l & 15, q = l >> 4;
    const int m0 = blockIdx.x * 128, n0 = blockIdx.y * 256;

    // staging: thread covers row (chunk*64 + (tid>>3)), 16B at inverse-swizzled col; dest linear
    const int srow = tid >> 3;
    const int scol = ((tid & 7) ^ (srow & 7)) << 3;
    const u16* Ag = A  + (size_t)(m0 + srow) * 1024 + scol;
    const u16* Bg = BT + (size_t)(n0 + srow) * 1024 + scol;
    const int sd = tid * 8;

    // fragment read offsets (u16): phys = row*64 + (col ^ ((row&7)<<3)); row&7 == fr&7
    const int colk0 = (q*8)      ^ ((fr & 7) << 3);
    const int colk1 = (32 + q*8) ^ ((fr & 7) << 3);
    const int aoff = (wr*64 + fr) * 64;
    const int boff = 8192 + (wc*64 + fr) * 64;

    f32x4 acc[4][4] = {};
    bf16x8 af[4][2], bf[2][2];

    auto stgA = [&](int buf, int kt){
#pragma unroll
        for (int i = 0; i < 2; ++i)
            gl_lds16(Ag + (size_t)(i*64)*1024 + kt*64, &lds[buf][i*4096 + sd]);
    };
    auto stgB = [&](int buf, int kt){
#pragma unroll
        for (int j = 0; j < 4; ++j)
            gl_lds16(Bg + (size_t)(j*64)*1024 + kt*64, &lds[buf][8192 + j*4096 + sd]);
    };

    // prologue: A(0),B(0),A(1) = 8 issues; vmcnt(2) retires tile 0 (leaves A(1)x2)
    stgA(0, 0); stgB(0, 0); stgA(1, 1);
    asm volatile("s_waitcnt vmcnt(2)" ::: "memory");
    SCB;
    BARRIER();

#pragma unroll 1
    for (int uu = 0; uu < 8; ++uu){
        const bool s = (uu < 7);

#pragma unroll
        for (int par = 0; par < 2; ++par){      // par=0: tile u=2uu (buf0); par=1: u=2uu+1 (buf1)
            u16* Lb = &lds[par][0];
            const int ktB = 2*uu + 1 + par;     // B(u+1)
            const int ktA = 2*uu + 2 + par;     // A(u+2)
            const bool sB = (par == 0) ? true : s;
            const bool sA = s;

            // ---- P1: read af(8)+bf01(4); stage B(u+1) into other buf; MFMA nt0-1 ----
#pragma unroll
            for (int mt = 0; mt < 4; ++mt){
                af[mt][0] = LD8(Lb + aoff + mt*1024 + colk0);
                af[mt][1] = LD8(Lb + aoff + mt*1024 + colk1);
            }
#pragma unroll
            for (int nt = 0; nt < 2; ++nt){
                bf[nt][0] = LD8(Lb + boff + nt*1024 + colk0);
                bf[nt][1] = LD8(Lb + boff + nt*1024 + colk1);
            }
            if (sB) stgB(par ^ 1, ktB);
            PHASE_GATE();
            __builtin_amdgcn_s_setprio(1);
#pragma unroll
            for (int mt = 0; mt < 4; ++mt)
#pragma unroll
                for (int nt = 0; nt < 2; ++nt){
                    acc[mt][nt] = __builtin_amdgcn_mfma_f32_16x16x32_bf16(af[mt][0], bf[nt][0], acc[mt][nt], 0, 0, 0);
                    acc[mt][nt] = __builtin_amdgcn_mfma_f32_16x16x32_bf16(af[mt][1], bf[nt][1], acc[mt][nt], 0, 0, 0);
                }
            __builtin_amdgcn_s_setprio(0);
            SCB;
            BARRIER();

            // ---- P2: read bf23(4); stage A(u+2) into own buf-A; MFMA nt2-3; vmcnt gate ----
#pragma unroll
            for (int nt = 0; nt < 2; ++nt){
                bf[nt][0] = LD8(Lb + boff + (2+nt)*1024 + colk0);
                bf[nt][1] = LD8(Lb + boff + (2+nt)*1024 + colk1);
            }
            if (sA) stgA(par, ktA);
            PHASE_GATE();
            __builtin_amdgcn_s_setprio(1);
#pragma unroll
            for (int mt = 0; mt < 4; ++mt)
#pragma unroll
                for (int nt = 0; nt < 2; ++nt){
                    acc[mt][2+nt] = __builtin_amdgcn_mfma_f32_16x16x32_bf16(af[mt][0], bf[nt][0], acc[mt][2+nt], 0, 0, 0);
                    acc[mt][2+nt] = __builtin_amdgcn_mfma_f32_16x16x32_bf16(af[mt][1], bf[nt][1], acc[mt][2+nt], 0, 0, 0);
                }
            __builtin_amdgcn_s_setprio(0);
            SCB;
            if (sA) asm volatile("s_waitcnt vmcnt(2)" ::: "memory");
            else    asm volatile("s_waitcnt vmcnt(0)" ::: "memory");
            SCB;
            BARRIER();
        }
    }

    // epilogue: C/D layout col=lane&15 (N), row=(lane>>4)*4+r (M)
#pragma unroll
    for (int mt = 0; mt < 4; ++mt){
        int row0 = m0 + wr*64 + mt*16 + q*4;
#pragma unroll
        for (int nt = 0; nt < 4; ++nt){
            int col = n0 + wc*64 + nt*16 + fr;
#pragma unroll
            for (int r = 0; r < 4; ++r){
                float val = acc[mt][nt][r];
                int row = row0 + r;
                if (MODE == 2){
                    outf[(size_t)row*1024 + col] = val;
                } else {
                    int which = col >> 10, colw = col & 1023;
                    int h = colw >> 6, d = colw & 63;
                    int bb = row >> 11, tt = row & 2047;
                    outh[(size_t)which*8388608 + (((size_t)(bb*16 + h))*2048 + tt)*64 + d] = f2b(val);
                }
            }
        }
    }
}

// ---------- FAVOR+ feature map via MFMA (q path): phi = exp(x.Wf - 0.5||x||^2)/sqrt(NF) ----------
__global__ __launch_bounds__(256) void featmap_mfma(const u16* __restrict__ xh, const float* __restrict__ Wf,
                                                    u16* __restrict__ xp)
{
    __shared__ u16 Xl[128][72];
    __shared__ u16 Wft[128][72];
    __shared__ float sqp[128][8];
    __shared__ float sql[128];
    int tid = threadIdx.x;
    int lane = tid & 63, w = tid >> 6;
    int m = lane & 15, q = lane >> 4;
    const u16* xb = xh + (size_t)blockIdx.x * 128 * 64;
#pragma unroll
    for (int it = 0; it < 4; it++){
        int idx = tid + 256*it;
        int row = idx >> 3, c8 = (idx & 7) * 8;
        uint4 v = *reinterpret_cast<const uint4*>(xb + (size_t)row*64 + c8);
        *reinterpret_cast<uint4*>(&Xl[row][c8]) = v;
        u32 ww[4] = {v.x, v.y, v.z, v.w};
        float s = 0.f;
#pragma unroll
        for (int j = 0; j < 4; j++){
            float a = b2f_lo(ww[j]), bb = b2f_hi(ww[j]);
            s += a*a + bb*bb;
        }
        sqp[row][idx & 7] = s;
    }
#pragma unroll
    for (int it = 0; it < 8; it++){
        int idx = tid + 256*it;
        int d = idx >> 5, f4 = (idx & 31) * 4;
        float4 v = *reinterpret_cast<const float4*>(Wf + d*128 + f4);
        Wft[f4+0][d] = f2b(v.x); Wft[f4+1][d] = f2b(v.y);
        Wft[f4+2][d] = f2b(v.z); Wft[f4+3][d] = f2b(v.w);
    }
    __syncthreads();
    if (tid < 128){
        float s = 0.f;
#pragma unroll
        for (int j = 0; j < 8; j++) s += sqp[tid][j];
        sql[tid] = s;
    }
    f32x4 acc[2][8] = {};
#pragma unroll
    for (int ks = 0; ks < 2; ks++){
        bf16x8 af[2], bf[8];
#pragma unroll
        for (int mt = 0; mt < 2; mt++)
            af[mt] = *reinterpret_cast<const bf16x8*>(&Xl[32*w + mt*16 + m][ks*32 + q*8]);
#pragma unroll
        for (int nt = 0; nt < 8; nt++)
            bf[nt] = *reinterpret_cast<const bf16x8*>(&Wft[nt*16 + m][ks*32 + q*8]);
#pragma unroll
        for (int mt = 0; mt < 2; mt++)
#pragma unroll
            for (int nt = 0; nt < 8; nt++)
                acc[mt][nt] = __builtin_amdgcn_mfma_f32_16x16x32_bf16(af[mt], bf[nt], acc[mt][nt], 0, 0, 0);
    }
    __syncthreads();
    const float c = 0.08838834764831845f; // 1/sqrt(128)
    u16* xpb = xp + (size_t)blockIdx.x * 128 * 128;
#pragma unroll
    for (int mt = 0; mt < 2; mt++){
#pragma unroll
        for (int r = 0; r < 4; r++){
            int t = 32*w + mt*16 + q*4 + r;
            float hs = 0.5f * sql[t];
#pragma unroll
            for (int nt = 0; nt < 8; nt++){
                int f = nt*16 + m;
                xpb[(size_t)t*128 + f] = f2b(__expf(fminf(acc[mt][nt][r] - hs, 60.f)) * c);
            }
        }
    }
}

// ---------- k path: featmap + per-chunk KV summary fused ----------
// One block = one (bh, chunk): computes kp = phi(k), S^T[d][f] = V^T.kp (MFMA), z = colsum(kp).
struct FM1 { u16 Xl[128][72]; u16 Wft[128][72]; };
union  FMU { FM1 p1; u16 Kpt[128][136]; };
__global__ __launch_bounds__(256) void featmap_sum(const u16* __restrict__ kh, const float* __restrict__ Wf,
                                                   const u16* __restrict__ vh, u16* __restrict__ kp,
                                                   u16* __restrict__ Sa, float* __restrict__ zs)
{
    __shared__ FMU sm;
    __shared__ u16 Vt[64][136];
    __shared__ float sqp[128][8];
    __shared__ float sql[128];
    int blk = blockIdx.x, tid = threadIdx.x;
    int lane = tid & 63, w = tid >> 6;
    int m = lane & 15, q = lane >> 4;
    const u16* xb = kh + (size_t)blk * 128 * 64;
    const u16* vb = vh + (size_t)blk * 128 * 64;   // same (bh,chunk) flat layout
    // stage K-chunk + sq partials
#pragma unroll
    for (int it = 0; it < 4; it++){
        int idx = tid + 256*it;
        int row = idx >> 3, c8 = (idx & 7) * 8;
        uint4 v = *reinterpret_cast<const uint4*>(xb + (size_t)row*64 + c8);
        *reinterpret_cast<uint4*>(&sm.p1.Xl[row][c8]) = v;
        u32 ww[4] = {v.x, v.y, v.z, v.w};
        float s = 0.f;
#pragma unroll
        for (int j = 0; j < 4; j++){
            float a = b2f_lo(ww[j]), bb = b2f_hi(ww[j]);
            s += a*a + bb*bb;
        }
        sqp[row][idx & 7] = s;
    }
    // stage Wf^T
#pragma unroll
    for (int it = 0; it < 8; it++){
        int idx = tid + 256*it;
        int d = idx >> 5, f4 = (idx & 31) * 4;
        float4 v = *reinterpret_cast<const float4*>(Wf + d*128 + f4);
        sm.p1.Wft[f4+0][d] = f2b(v.x); sm.p1.Wft[f4+1][d] = f2b(v.y);
        sm.p1.Wft[f4+2][d] = f2b(v.z); sm.p1.Wft[f4+3][d] = f2b(v.w);
    }
    // stage V transposed
#pragma unroll
    for (int it = 0; it < 4; it++){
        int idx = tid + 256*it;
        int t = idx >> 3, d8 = (idx & 7)*8;
        uint4 v = *reinterpret_cast<const uint4*>(vb + (size_t)t*64 + d8);
        u32 ww[4] = {v.x, v.y, v.z, v.w};
#pragma unroll
        for (int j = 0; j < 4; j++){
            Vt[d8 + 2*j][t]     = (u16)(ww[j] & 0xFFFFu);
            Vt[d8 + 2*j + 1][t] = (u16)(ww[j] >> 16);
        }
    }
    __syncthreads();
    if (tid < 128){
        float s = 0.f;
#pragma unroll
        for (int j = 0; j < 8; j++) s += sqp[tid][j];
        sql[tid] = s;
    }
    // phi MFMA
    f32x4 acc[2][8] = {};
#pragma unroll
    for (int ks = 0; ks < 2; ks++){
        bf16x8 af[2], bf[8];
#pragma unroll
        for (int mt = 0; mt < 2; mt++)
            af[mt] = *reinterpret_cast<const bf16x8*>(&sm.p1.Xl[32*w + mt*16 + m][ks*32 + q*8]);
#pragma unroll
        for (int nt = 0; nt < 8; nt++)
            bf[nt] = *reinterpret_cast<const bf16x8*>(&sm.p1.Wft[nt*16 + m][ks*32 + q*8]);
#pragma unroll
        for (int mt = 0; mt < 2; mt++)
#pragma unroll
            for (int nt = 0; nt < 8; nt++)
                acc[mt][nt] = __builtin_amdgcn_mfma_f32_16x16x32_bf16(af[mt], bf[nt], acc[mt][nt], 0, 0, 0);
    }
    __syncthreads();   // Xl/Wft reads complete (region about to be overwritten), sql visible
    // epilogue: phi -> global kp AND transposed LDS Kpt[f][t]
    const float c = 0.08838834764831845f;
    u16* xpb = kp + (size_t)blk * 128 * 128;
#pragma unroll
    for (int mt = 0; mt < 2; mt++){
#pragma unroll
        for (int r = 0; r < 4; r++){
            int t = 32*w + mt*16 + q*4 + r;
            float hs = 0.5f * sql[t];
#pragma unroll
            for (int nt = 0; nt < 8; nt++){
                int f = nt*16 + m;
                u16 pv = f2b(__expf(fminf(acc[mt][nt][r] - hs, 60.f)) * c);
                xpb[(size_t)t*128 + f] = pv;
                sm.Kpt[f][t] = pv;
            }
        }
    }
    __syncthreads();   // Kpt ready
    // S^T = V^T . kp : A[d][t]=Vt, B[f][t]=Kpt ; wave w -> d rows [16w,16w+16)
    f32x4 acc2[8] = {};
#pragma unroll
    for (int ks = 0; ks < 4; ks++){
        bf16x8 af = *reinterpret_cast<const bf16x8*>(&Vt[16*w + m][ks*32 + q*8]);
        bf16x8 bf[8];
#pragma unroll
        for (int nt = 0; nt < 8; nt++)
            bf[nt] = *reinterpret_cast<const bf16x8*>(&sm.Kpt[nt*16 + m][ks*32 + q*8]);
#pragma unroll
        for (int nt = 0; nt < 8; nt++)
            acc2[nt] = __builtin_amdgcn_mfma_f32_16x16x32_bf16(af, bf[nt], acc2[nt], 0, 0, 0);
    }
    u16* Sb = Sa + (size_t)blk*8192;
#pragma unroll
    for (int nt = 0; nt < 8; nt++){
#pragma unroll
        for (int r = 0; r < 4; r++){
            int d = 16*w + q*4 + r;
            int f = nt*16 + m;
            Sb[(size_t)d*128 + f] = f2b(acc2[nt][r]);
        }
    }
    // z = colsum(kp) from Kpt rows (17-stride bank walk: 2-way, free)
    if (tid < 128){
        float z = 0.f;
#pragma unroll
        for (int t = 0; t < 128; t++) z += b2f(sm.Kpt[tid][t]);
        zs[(size_t)blk*128 + tid] = z;
    }
}

// ---------- exclusive prefix over the 16 chunks (per bh), bf16 in/out ----------
__global__ __launch_bounds__(256) void prefix_chunks(const u16* __restrict__ Sa, u16* __restrict__ Sb,
                                                     float* __restrict__ zs)
{
    int bh = blockIdx.x, seg = blockIdx.y, tid = threadIdx.x;
    const u16* src = Sa + (size_t)bh*16*8192;
    u16*       dst = Sb + (size_t)bh*16*8192;
#pragma unroll
    for (int it = 0; it < 4; it++){
        int e = seg*1024 + it*256 + tid;
        float run = 0.f;
#pragma unroll
        for (int c = 0; c < 16; c++){
            float v = b2f(src[(size_t)c*8192 + e]);
            dst[(size_t)c*8192 + e] = f2b(run);
            run += v;
        }
    }
    if (seg == 0 && tid < 128){
        float run = 0.f; float* zp = zs + (size_t)bh*16*128 + tid;
#pragma unroll
        for (int c = 0; c < 16; c++){ float v = zp[c*128]; zp[c*128] = run; run += v; }
    }
}

// ---------- per-chunk output via MFMA; denominator fused as extra MFMA B-tiles ----------
__global__ __launch_bounds__(256) void chunk_out(const u16* __restrict__ qp, const u16* __restrict__ kp,
                                                 const u16* __restrict__ vh, const u16* __restrict__ St,
                                                 const float* __restrict__ zs, u16* __restrict__ y2d)
{
    __shared__ u16 P[128][136];
    __shared__ u16 Vt[64][136];
    __shared__ u16 zl[128];
    int blk = blockIdx.x, tid = threadIdx.x;
    int lane = tid & 63, w = tid >> 6;
    int m = lane & 15, q = lane >> 4;
    int bh = blk >> 4, c = blk & 15;
    int b = bh >> 4, h = bh & 15, t0 = c*128;
    const u16* qpb = qp + ((size_t)bh*2048 + t0)*128;
    const u16* kpb = kp + ((size_t)bh*2048 + t0)*128;
    const u16* vb  = vh + ((size_t)bh*2048 + t0)*64;
    const u16* Stb = St + (size_t)blk*8192;

    if (tid < 128) zl[tid] = f2b(zs[(size_t)blk*128 + tid]);
#pragma unroll
    for (int it = 0; it < 4; it++){
        int idx = tid + 256*it;
        int t = idx >> 3, d8 = (idx & 7)*8;
        uint4 v = *reinterpret_cast<const uint4*>(&vb[(size_t)t*64 + d8]);
        u32 ww[4] = {v.x, v.y, v.z, v.w};
#pragma unroll
        for (int j = 0; j < 4; j++){
            Vt[d8 + 2*j][t]     = (u16)(ww[j] & 0xFFFFu);
            Vt[d8 + 2*j + 1][t] = (u16)(ww[j] >> 16);
        }
    }
    {
        int row = tid >> 1, half = tid & 1;
        int i = row >> 4;
        for (int s2 = 16*(i + 1) + half*2; s2 < 128; s2 += 4)
            *reinterpret_cast<u32*>(&P[row][s2]) = 0;
    }
    {
        static const unsigned char TIa[36] = {0,1,1,2,2,2,3,3,3,3,4,4,4,4,4,
                                              5,5,5,5,5,5,6,6,6,6,6,6,6,7,7,7,7,7,7,7,7};
        static const unsigned char TJa[36] = {0,0,1,0,1,2,0,1,2,3,0,1,2,3,4,
                                              0,1,2,3,4,5,0,1,2,3,4,5,6,0,1,2,3,4,5,6,7};
        for (int idx = w; idx < 36; idx += 4){
            int i = TIa[idx], j = TJa[idx];
            f32x4 a = {};
            const u16* arow = qpb + (size_t)(i*16 + m)*128 + q*8;
            const u16* brow = kpb + (size_t)(j*16 + m)*128 + q*8;
#pragma unroll
            for (int ks = 0; ks < 4; ks++){
                bf16x8 af = *reinterpret_cast<const bf16x8*>(arow + ks*32);
                bf16x8 bf = *reinterpret_cast<const bf16x8*>(brow + ks*32);
                a = __builtin_amdgcn_mfma_f32_16x16x32_bf16(af, bf, a, 0, 0, 0);
            }
            int scol = j*16 + m;
#pragma unroll
            for (int r = 0; r < 4; r++){
                int trow = i*16 + q*4 + r;
                P[trow][scol] = (scol <= trow) ? f2b(a[r]) : (u16)0;
            }
        }
    }
    __syncthreads();
    f32x4 acc[2][4] = {};
    f32x4 accd[2] = {};
    bf16x8 ones;
#pragma unroll
    for (int i = 0; i < 8; i++) ones[i] = (__bf16)1.0f;
    for (int ks = 0; ks <= w; ks++){
        bf16x8 af[2], bf4[4];
#pragma unroll
        for (int mt = 0; mt < 2; mt++)
            af[mt] = *reinterpret_cast<const bf16x8*>(&P[32*w + mt*16 + m][ks*32 + q*8]);
#pragma unroll
        for (int nt = 0; nt < 4; nt++)
            bf4[nt] = *reinterpret_cast<const bf16x8*>(&Vt[nt*16 + m][ks*32 + q*8]);
#pragma unroll
        for (int mt = 0; mt < 2; mt++){
#pragma unroll
            for (int nt = 0; nt < 4; nt++)
                acc[mt][nt] = __builtin_amdgcn_mfma_f32_16x16x32_bf16(af[mt], bf4[nt], acc[mt][nt], 0, 0, 0);
            accd[mt] = __builtin_amdgcn_mfma_f32_16x16x32_bf16(af[mt], ones, accd[mt], 0, 0, 0);
        }
    }
#pragma unroll
    for (int ks = 0; ks < 4; ks++){
        bf16x8 af[2], bf4[4];
        bf16x8 zf = *reinterpret_cast<const bf16x8*>(&zl[ks*32 + q*8]);
#pragma unroll
        for (int mt = 0; mt < 2; mt++)
            af[mt] = *reinterpret_cast<const bf16x8*>(qpb + (size_t)(32*w + mt*16 + m)*128 + ks*32 + q*8);
#pragma unroll
        for (int nt = 0; nt < 4; nt++)
            bf4[nt] = *reinterpret_cast<const bf16x8*>(Stb + (size_t)(nt*16 + m)*128 + ks*32 + q*8);
#pragma unroll
        for (int mt = 0; mt < 2; mt++){
#pragma unroll
            for (int nt = 0; nt < 4; nt++)
                acc[mt][nt] = __builtin_amdgcn_mfma_f32_16x16x32_bf16(af[mt], bf4[nt], acc[mt][nt], 0, 0, 0);
            accd[mt] = __builtin_amdgcn_mfma_f32_16x16x32_bf16(af[mt], zf, accd[mt], 0, 0, 0);
        }
    }
#pragma unroll
    for (int mt = 0; mt < 2; mt++){
#pragma unroll
        for (int nt = 0; nt < 4; nt++){
#pragma unroll
            for (int r = 0; r < 4; r++){
                int t = 32*w + mt*16 + q*4 + r;
                int d = nt*16 + m;
                float den = accd[mt][r] + 1e-6f;
                y2d[((size_t)b*2048 + t0 + t)*1024 + h*64 + d] = f2b(acc[mt][nt][r] / den);
            }
        }
    }
}

extern "C" void kernel_launch(void* const* d_in, const int* in_sizes, int n_in,
                              void* d_out, int out_size, void* d_ws, size_t ws_size,
                              hipStream_t stream)
{
    (void)in_sizes; (void)n_in; (void)out_size; (void)ws_size;
    const float* x  = (const float*)d_in[0];
    const float* Wq = (const float*)d_in[1];
    const float* Wk = (const float*)d_in[2];
    const float* Wv = (const float*)d_in[3];
    const float* Wo = (const float*)d_in[4];
    const float* Wf = (const float*)d_in[5];
    float* out = (float*)d_out;
    char* ws = (char*)d_ws;

    // workspace layout (lifetime-aliased, ~136.5 MiB)
    u16*   xh    = (u16*)  (ws + 0);           // 16MB x bf16 (dead after QKV gemm)
    u16*   Sa    = (u16*)  (ws + 0);           // alias xh: chunk S^T raw bf16
    u16*   qh    = (u16*)  (ws + 16777216);    // 16MB (dead after featmap q)
    u16*   Sbp   = (u16*)  (ws + 16777216);    // alias qh: prefix S^T
    u16*   kh    = (u16*)  (ws + 33554432);    // 16MB (dead after featmap_sum)
    u16*   y2d   = (u16*)  (ws + 33554432);    // alias kh
    u16*   vh    = (u16*)  (ws + 50331648);    // 16MB
    u16*   qp    = (u16*)  (ws + 67108864);    // 32MB
    u16*   kp    = (u16*)  (ws + 100663296);   // 32MB
    u16*   WTqkv = (u16*)  (ws + 134217728);   // 6MB (3 x 1024x1024 bf16)
    u16*   WTo   = (u16*)  (ws + 140509184);   // 2MB
    float* zs    = (float*)(ws + 142606336);   // 0.5MB

    tobf16<<<4096, 256, 0, stream>>>(x, xh);
    transpose_all<<<dim3(16, 16, 4), 256, 0, stream>>>(Wq, Wk, Wv, Wo, WTqkv, WTo);

    // fused QKV: writes qh, kh, vh (contiguous 16MB blocks starting at qh); 768 blocks = 3 exact rounds
    gemm_2p<3><<<dim3(64, 12), 512, 0, stream>>>(xh, WTqkv, nullptr, qh);

    featmap_mfma<<<1024, 256, 0, stream>>>(qh, Wf, qp);
    featmap_sum<<<1024, 256, 0, stream>>>(kh, Wf, vh, kp, Sa, zs);

    prefix_chunks<<<dim3(64, 8), 256, 0, stream>>>(Sa, Sbp, zs);
    chunk_out<<<1024, 256, 0, stream>>>(qp, kp, vh, Sbp, zs, y2d);

    // out-proj: 256 blocks = 1 exact round
    gemm_2p<2><<<dim3(64, 4), 512, 0, stream>>>(y2d, WTo, out, nullptr);
}

// Round 4
// 282.626 us; speedup vs baseline: 1.0484x; 1.0365x over previous
//
#include <hip/hip_runtime.h>
#include <hip/hip_bf16.h>

typedef unsigned int u32;
typedef unsigned short u16;
typedef __bf16 bf16x8 __attribute__((ext_vector_type(8)));
typedef float f32x4 __attribute__((ext_vector_type(4)));

// ---------- bf16 bit helpers ----------
__device__ __forceinline__ float b2f(u16 s){ union{u32 x; float f;} c; c.x = ((u32)s) << 16; return c.f; }
__device__ __forceinline__ float b2f_lo(u32 u){ union{u32 x; float f;} c; c.x = u << 16; return c.f; }
__device__ __forceinline__ float b2f_hi(u32 u){ union{u32 x; float f;} c; c.x = u & 0xFFFF0000u; return c.f; }
__device__ __forceinline__ u16 f2b(float f){
    union{float f; u32 u;} c; c.f = f;
    u32 r = c.u + 0x7FFFu + ((c.u >> 16) & 1u);
    return (u16)(r >> 16);
}
__device__ __forceinline__ u32 pk(float lo, float hi){
    return (u32)f2b(lo) | ((u32)f2b(hi) << 16);
}
// async global->LDS, 16B per lane (HW: wave-uniform base + lane*16)
__device__ __forceinline__ void gl_lds16(const u16* g, u16* l){
    __builtin_amdgcn_global_load_lds(
        (const __attribute__((address_space(1))) void*)g,
        (__attribute__((address_space(3))) void*)l, 16, 0, 0);
}
#define BARRIER() do { __builtin_amdgcn_s_barrier(); asm volatile("" ::: "memory"); } while(0)
#define SCB __builtin_amdgcn_sched_barrier(0)
#define PHASE_GATE() do { asm volatile("" ::: "memory"); __builtin_amdgcn_s_barrier(); \
    asm volatile("s_waitcnt lgkmcnt(0)" ::: "memory"); SCB; } while(0)
#define LD8(p) (*reinterpret_cast<const bf16x8*>(p))

// Problem constants: B=4, T=2048, D=1024, H=16, HD=64, NF=128, chunk C=128, NC=16
// All inputs FLOAT32; OUTPUT is FLOAT32.

// ---------- fp32 -> bf16 bulk convert (x) ----------
__global__ __launch_bounds__(256) void tobf16(const float* __restrict__ in, u16* __restrict__ out)
{
    size_t i = ((size_t)blockIdx.x * 256 + threadIdx.x) * 8;
    float4 a = *reinterpret_cast<const float4*>(in + i);
    float4 b = *reinterpret_cast<const float4*>(in + i + 4);
    uint4 v; v.x = pk(a.x, a.y); v.y = pk(a.z, a.w); v.z = pk(b.x, b.y); v.w = pk(b.z, b.w);
    *reinterpret_cast<uint4*>(out + i) = v;
}

// ---------- all 4 weight transposes (+fp32->bf16) in one dispatch ----------
__global__ __launch_bounds__(256) void transpose_all(const float* __restrict__ Wq, const float* __restrict__ Wk,
                                                     const float* __restrict__ Wv, const float* __restrict__ Wo,
                                                     u16* __restrict__ WTqkv, u16* __restrict__ WTo)
{
    const float* in; u16* out;
    switch (blockIdx.z){
        case 0:  in = Wq; out = WTqkv;           break;
        case 1:  in = Wk; out = WTqkv + 1048576; break;
        case 2:  in = Wv; out = WTqkv + 2097152; break;
        default: in = Wo; out = WTo;             break;
    }
    __shared__ u16 tile[64][72];
    int kb = blockIdx.x * 64, nb = blockIdx.y * 64, tid = threadIdx.x;
#pragma unroll
    for (int i = 0; i < 2; i++){
        int idx = tid + 256*i; int r = idx >> 3; int c8 = (idx & 7) * 8;
        const float* p = &in[(size_t)(kb + r)*1024 + nb + c8];
        float4 lo = *reinterpret_cast<const float4*>(p);
        float4 hi = *reinterpret_cast<const float4*>(p + 4);
        uint4 v;
        v.x = pk(lo.x, lo.y); v.y = pk(lo.z, lo.w);
        v.z = pk(hi.x, hi.y); v.w = pk(hi.z, hi.w);
        *reinterpret_cast<uint4*>(&tile[r][c8]) = v;
    }
    __syncthreads();
#pragma unroll
    for (int i = 0; i < 2; i++){
        int idx = tid + 256*i; int c = idx >> 3; int r8 = (idx & 7) * 8;
        u32 w[4];
#pragma unroll
        for (int j = 0; j < 4; j++)
            w[j] = (u32)tile[r8 + 2*j][c] | ((u32)tile[r8 + 2*j + 1][c] << 16);
        uint4 v; v.x = w[0]; v.y = w[1]; v.z = w[2]; v.w = w[3];
        *reinterpret_cast<uint4*>(&out[(size_t)(nb + c)*1024 + kb + r8]) = v;
    }
}

// ---------- 2-phase/K-tile counted-vmcnt GEMM: tile 128x256, BK=64, 8 waves (2Mx4N), per-wave 64x64 ----------
// (unchanged from round 3 — verified 0 bank conflicts, exact-round grids)
template<int MODE>
__global__ __launch_bounds__(512, 2) void gemm_2p(const u16* __restrict__ A, const u16* __restrict__ BT,
                                                  float* __restrict__ outf, u16* __restrict__ outh)
{
    __shared__ u16 lds[2][24576];
    const int tid = threadIdx.x;
    const int l = tid & 63, w = tid >> 6;
    const int wr = w >> 2, wc = w & 3;          // 2M x 4N wave grid, per-wave 64x64
    const int fr = l & 15, q = l >> 4;
    const int m0 = blockIdx.x * 128, n0 = blockIdx.y * 256;

    const int srow = tid >> 3;
    const int scol = ((tid & 7) ^ (srow & 7)) << 3;
    const u16* Ag = A  + (size_t)(m0 + srow) * 1024 + scol;
    const u16* Bg = BT + (size_t)(n0 + srow) * 1024 + scol;
    const int sd = tid * 8;

    const int colk0 = (q*8)      ^ ((fr & 7) << 3);
    const int colk1 = (32 + q*8) ^ ((fr & 7) << 3);
    const int aoff = (wr*64 + fr) * 64;
    const int boff = 8192 + (wc*64 + fr) * 64;

    f32x4 acc[4][4] = {};
    bf16x8 af[4][2], bf[2][2];

    auto stgA = [&](int buf, int kt){
#pragma unroll
        for (int i = 0; i < 2; ++i)
            gl_lds16(Ag + (size_t)(i*64)*1024 + kt*64, &lds[buf][i*4096 + sd]);
    };
    auto stgB = [&](int buf, int kt){
#pragma unroll
        for (int j = 0; j < 4; ++j)
            gl_lds16(Bg + (size_t)(j*64)*1024 + kt*64, &lds[buf][8192 + j*4096 + sd]);
    };

    // prologue: A(0),B(0),A(1) = 8 issues; vmcnt(2) retires tile 0 (leaves A(1)x2)
    stgA(0, 0); stgB(0, 0); stgA(1, 1);
    asm volatile("s_waitcnt vmcnt(2)" ::: "memory");
    SCB;
    BARRIER();

#pragma unroll 1
    for (int uu = 0; uu < 8; ++uu){
        const bool s = (uu < 7);

#pragma unroll
        for (int par = 0; par < 2; ++par){      // par=0: tile u=2uu (buf0); par=1: u=2uu+1 (buf1)
            u16* Lb = &lds[par][0];
            const int ktB = 2*uu + 1 + par;     // B(u+1)
            const int ktA = 2*uu + 2 + par;     // A(u+2)
            const bool sB = (par == 0) ? true : s;
            const bool sA = s;

            // ---- P1: read af(8)+bf01(4); stage B(u+1) into other buf; MFMA nt0-1 ----
#pragma unroll
            for (int mt = 0; mt < 4; ++mt){
                af[mt][0] = LD8(Lb + aoff + mt*1024 + colk0);
                af[mt][1] = LD8(Lb + aoff + mt*1024 + colk1);
            }
#pragma unroll
            for (int nt = 0; nt < 2; ++nt){
                bf[nt][0] = LD8(Lb + boff + nt*1024 + colk0);
                bf[nt][1] = LD8(Lb + boff + nt*1024 + colk1);
            }
            if (sB) stgB(par ^ 1, ktB);
            PHASE_GATE();
            __builtin_amdgcn_s_setprio(1);
#pragma unroll
            for (int mt = 0; mt < 4; ++mt)
#pragma unroll
                for (int nt = 0; nt < 2; ++nt){
                    acc[mt][nt] = __builtin_amdgcn_mfma_f32_16x16x32_bf16(af[mt][0], bf[nt][0], acc[mt][nt], 0, 0, 0);
                    acc[mt][nt] = __builtin_amdgcn_mfma_f32_16x16x32_bf16(af[mt][1], bf[nt][1], acc[mt][nt], 0, 0, 0);
                }
            __builtin_amdgcn_s_setprio(0);
            SCB;
            BARRIER();

            // ---- P2: read bf23(4); stage A(u+2) into own buf-A; MFMA nt2-3; vmcnt gate ----
#pragma unroll
            for (int nt = 0; nt < 2; ++nt){
                bf[nt][0] = LD8(Lb + boff + (2+nt)*1024 + colk0);
                bf[nt][1] = LD8(Lb + boff + (2+nt)*1024 + colk1);
            }
            if (sA) stgA(par, ktA);
            PHASE_GATE();
            __builtin_amdgcn_s_setprio(1);
#pragma unroll
            for (int mt = 0; mt < 4; ++mt)
#pragma unroll
                for (int nt = 0; nt < 2; ++nt){
                    acc[mt][2+nt] = __builtin_amdgcn_mfma_f32_16x16x32_bf16(af[mt][0], bf[nt][0], acc[mt][2+nt], 0, 0, 0);
                    acc[mt][2+nt] = __builtin_amdgcn_mfma_f32_16x16x32_bf16(af[mt][1], bf[nt][1], acc[mt][2+nt], 0, 0, 0);
                }
            __builtin_amdgcn_s_setprio(0);
            SCB;
            if (sA) asm volatile("s_waitcnt vmcnt(2)" ::: "memory");
            else    asm volatile("s_waitcnt vmcnt(0)" ::: "memory");
            SCB;
            BARRIER();
        }
    }

    // epilogue: C/D layout col=lane&15 (N), row=(lane>>4)*4+r (M)
#pragma unroll
    for (int mt = 0; mt < 4; ++mt){
        int row0 = m0 + wr*64 + mt*16 + q*4;
#pragma unroll
        for (int nt = 0; nt < 4; ++nt){
            int col = n0 + wc*64 + nt*16 + fr;
#pragma unroll
            for (int r = 0; r < 4; ++r){
                float val = acc[mt][nt][r];
                int row = row0 + r;
                if (MODE == 2){
                    outf[(size_t)row*1024 + col] = val;
                } else {
                    int which = col >> 10, colw = col & 1023;
                    int h = colw >> 6, d = colw & 63;
                    int bb = row >> 11, tt = row & 2047;
                    outh[(size_t)which*8388608 + (((size_t)(bb*16 + h))*2048 + tt)*64 + d] = f2b(val);
                }
            }
        }
    }
}

// ---------- FAVOR+ feature map via MFMA (q path): phi = exp(x.Wf - 0.5||x||^2)/sqrt(NF) ----------
__global__ __launch_bounds__(256) void featmap_mfma(const u16* __restrict__ xh, const float* __restrict__ Wf,
                                                    u16* __restrict__ xp)
{
    __shared__ u16 Xl[128][72];
    __shared__ u16 Wft[128][72];
    __shared__ float sqp[128][8];
    __shared__ float sql[128];
    int tid = threadIdx.x;
    int lane = tid & 63, w = tid >> 6;
    int m = lane & 15, q = lane >> 4;
    const u16* xb = xh + (size_t)blockIdx.x * 128 * 64;
#pragma unroll
    for (int it = 0; it < 4; it++){
        int idx = tid + 256*it;
        int row = idx >> 3, c8 = (idx & 7) * 8;
        uint4 v = *reinterpret_cast<const uint4*>(xb + (size_t)row*64 + c8);
        *reinterpret_cast<uint4*>(&Xl[row][c8]) = v;
        u32 ww[4] = {v.x, v.y, v.z, v.w};
        float s = 0.f;
#pragma unroll
        for (int j = 0; j < 4; j++){
            float a = b2f_lo(ww[j]), bb = b2f_hi(ww[j]);
            s += a*a + bb*bb;
        }
        sqp[row][idx & 7] = s;
    }
#pragma unroll
    for (int it = 0; it < 8; it++){
        int idx = tid + 256*it;
        int d = idx >> 5, f4 = (idx & 31) * 4;
        float4 v = *reinterpret_cast<const float4*>(Wf + d*128 + f4);
        Wft[f4+0][d] = f2b(v.x); Wft[f4+1][d] = f2b(v.y);
        Wft[f4+2][d] = f2b(v.z); Wft[f4+3][d] = f2b(v.w);
    }
    __syncthreads();
    if (tid < 128){
        float s = 0.f;
#pragma unroll
        for (int j = 0; j < 8; j++) s += sqp[tid][j];
        sql[tid] = s;
    }
    f32x4 acc[2][8] = {};
#pragma unroll
    for (int ks = 0; ks < 2; ks++){
        bf16x8 af[2], bf[8];
#pragma unroll
        for (int mt = 0; mt < 2; mt++)
            af[mt] = *reinterpret_cast<const bf16x8*>(&Xl[32*w + mt*16 + m][ks*32 + q*8]);
#pragma unroll
        for (int nt = 0; nt < 8; nt++)
            bf[nt] = *reinterpret_cast<const bf16x8*>(&Wft[nt*16 + m][ks*32 + q*8]);
#pragma unroll
        for (int mt = 0; mt < 2; mt++)
#pragma unroll
            for (int nt = 0; nt < 8; nt++)
                acc[mt][nt] = __builtin_amdgcn_mfma_f32_16x16x32_bf16(af[mt], bf[nt], acc[mt][nt], 0, 0, 0);
    }
    __syncthreads();
    const float c = 0.08838834764831845f; // 1/sqrt(128)
    u16* xpb = xp + (size_t)blockIdx.x * 128 * 128;
#pragma unroll
    for (int mt = 0; mt < 2; mt++){
#pragma unroll
        for (int r = 0; r < 4; r++){
            int t = 32*w + mt*16 + q*4 + r;
            float hs = 0.5f * sql[t];
#pragma unroll
            for (int nt = 0; nt < 8; nt++){
                int f = nt*16 + m;
                xpb[(size_t)t*128 + f] = f2b(__expf(fminf(acc[mt][nt][r] - hs, 60.f)) * c);
            }
        }
    }
}

// ---------- k path: featmap + per-chunk KV summary fused ----------
// One block = one (bh, chunk): computes kp = phi(k), S^T[d][f] = V^T.kp (MFMA), z = colsum(kp).
struct FM1 { u16 Xl[128][72]; u16 Wft[128][72]; };
union  FMU { FM1 p1; u16 Kpt[128][136]; };
__global__ __launch_bounds__(256) void featmap_sum(const u16* __restrict__ kh, const float* __restrict__ Wf,
                                                   const u16* __restrict__ vh, u16* __restrict__ kp,
                                                   u16* __restrict__ Sa, float* __restrict__ zs)
{
    __shared__ FMU sm;
    __shared__ u16 Vt[64][136];
    __shared__ float sqp[128][8];
    __shared__ float sql[128];
    int blk = blockIdx.x, tid = threadIdx.x;
    int lane = tid & 63, w = tid >> 6;
    int m = lane & 15, q = lane >> 4;
    const u16* xb = kh + (size_t)blk * 128 * 64;
    const u16* vb = vh + (size_t)blk * 128 * 64;   // same (bh,chunk) flat layout
    // stage K-chunk + sq partials
#pragma unroll
    for (int it = 0; it < 4; it++){
        int idx = tid + 256*it;
        int row = idx >> 3, c8 = (idx & 7) * 8;
        uint4 v = *reinterpret_cast<const uint4*>(xb + (size_t)row*64 + c8);
        *reinterpret_cast<uint4*>(&sm.p1.Xl[row][c8]) = v;
        u32 ww[4] = {v.x, v.y, v.z, v.w};
        float s = 0.f;
#pragma unroll
        for (int j = 0; j < 4; j++){
            float a = b2f_lo(ww[j]), bb = b2f_hi(ww[j]);
            s += a*a + bb*bb;
        }
        sqp[row][idx & 7] = s;
    }
    // stage Wf^T
#pragma unroll
    for (int it = 0; it < 8; it++){
        int idx = tid + 256*it;
        int d = idx >> 5, f4 = (idx & 31) * 4;
        float4 v = *reinterpret_cast<const float4*>(Wf + d*128 + f4);
        sm.p1.Wft[f4+0][d] = f2b(v.x); sm.p1.Wft[f4+1][d] = f2b(v.y);
        sm.p1.Wft[f4+2][d] = f2b(v.z); sm.p1.Wft[f4+3][d] = f2b(v.w);
    }
    // stage V transposed
#pragma unroll
    for (int it = 0; it < 4; it++){
        int idx = tid + 256*it;
        int t = idx >> 3, d8 = (idx & 7)*8;
        uint4 v = *reinterpret_cast<const uint4*>(vb + (size_t)t*64 + d8);
        u32 ww[4] = {v.x, v.y, v.z, v.w};
#pragma unroll
        for (int j = 0; j < 4; j++){
            Vt[d8 + 2*j][t]     = (u16)(ww[j] & 0xFFFFu);
            Vt[d8 + 2*j + 1][t] = (u16)(ww[j] >> 16);
        }
    }
    __syncthreads();
    if (tid < 128){
        float s = 0.f;
#pragma unroll
        for (int j = 0; j < 8; j++) s += sqp[tid][j];
        sql[tid] = s;
    }
    // phi MFMA
    f32x4 acc[2][8] = {};
#pragma unroll
    for (int ks = 0; ks < 2; ks++){
        bf16x8 af[2], bf[8];
#pragma unroll
        for (int mt = 0; mt < 2; mt++)
            af[mt] = *reinterpret_cast<const bf16x8*>(&sm.p1.Xl[32*w + mt*16 + m][ks*32 + q*8]);
#pragma unroll
        for (int nt = 0; nt < 8; nt++)
            bf[nt] = *reinterpret_cast<const bf16x8*>(&sm.p1.Wft[nt*16 + m][ks*32 + q*8]);
#pragma unroll
        for (int mt = 0; mt < 2; mt++)
#pragma unroll
            for (int nt = 0; nt < 8; nt++)
                acc[mt][nt] = __builtin_amdgcn_mfma_f32_16x16x32_bf16(af[mt], bf[nt], acc[mt][nt], 0, 0, 0);
    }
    __syncthreads();   // Xl/Wft reads complete (region about to be overwritten), sql visible
    // epilogue: phi -> global kp AND transposed LDS Kpt[f][t]
    const float c = 0.08838834764831845f;
    u16* xpb = kp + (size_t)blk * 128 * 128;
#pragma unroll
    for (int mt = 0; mt < 2; mt++){
#pragma unroll
        for (int r = 0; r < 4; r++){
            int t = 32*w + mt*16 + q*4 + r;
            float hs = 0.5f * sql[t];
#pragma unroll
            for (int nt = 0; nt < 8; nt++){
                int f = nt*16 + m;
                u16 pv = f2b(__expf(fminf(acc[mt][nt][r] - hs, 60.f)) * c);
                xpb[(size_t)t*128 + f] = pv;
                sm.Kpt[f][t] = pv;
            }
        }
    }
    __syncthreads();   // Kpt ready
    // S^T = V^T . kp : A[d][t]=Vt, B[f][t]=Kpt ; wave w -> d rows [16w,16w+16)
    f32x4 acc2[8] = {};
#pragma unroll
    for (int ks = 0; ks < 4; ks++){
        bf16x8 af = *reinterpret_cast<const bf16x8*>(&Vt[16*w + m][ks*32 + q*8]);
        bf16x8 bf[8];
#pragma unroll
        for (int nt = 0; nt < 8; nt++)
            bf[nt] = *reinterpret_cast<const bf16x8*>(&sm.Kpt[nt*16 + m][ks*32 + q*8]);
#pragma unroll
        for (int nt = 0; nt < 8; nt++)
            acc2[nt] = __builtin_amdgcn_mfma_f32_16x16x32_bf16(af, bf[nt], acc2[nt], 0, 0, 0);
    }
    u16* Sb = Sa + (size_t)blk*8192;
#pragma unroll
    for (int nt = 0; nt < 8; nt++){
#pragma unroll
        for (int r = 0; r < 4; r++){
            int d = 16*w + q*4 + r;
            int f = nt*16 + m;
            Sb[(size_t)d*128 + f] = f2b(acc2[nt][r]);
        }
    }
    // z = colsum(kp) from Kpt rows (17-stride bank walk: 2-way, free)
    if (tid < 128){
        float z = 0.f;
#pragma unroll
        for (int t = 0; t < 128; t++) z += b2f(sm.Kpt[tid][t]);
        zs[(size_t)blk*128 + tid] = z;
    }
}

// ---------- exclusive prefix over the 16 chunks (per bh), bf16 in/out ----------
__global__ __launch_bounds__(256) void prefix_chunks(const u16* __restrict__ Sa, u16* __restrict__ Sb,
                                                     float* __restrict__ zs)
{
    int bh = blockIdx.x, seg = blockIdx.y, tid = threadIdx.x;
    const u16* src = Sa + (size_t)bh*16*8192;
    u16*       dst = Sb + (size_t)bh*16*8192;
#pragma unroll
    for (int it = 0; it < 4; it++){
        int e = seg*1024 + it*256 + tid;
        float run = 0.f;
#pragma unroll
        for (int c = 0; c < 16; c++){
            float v = b2f(src[(size_t)c*8192 + e]);
            dst[(size_t)c*8192 + e] = f2b(run);
            run += v;
        }
    }
    if (seg == 0 && tid < 128){
        float run = 0.f; float* zp = zs + (size_t)bh*16*128 + tid;
#pragma unroll
        for (int c = 0; c < 16; c++){ float v = zp[c*128]; zp[c*128] = run; run += v; }
    }
}

// ---------- per-chunk output via MFMA, 8 waves, swizzled LDS (latency-bound fix) ----------
// One block = one (bh, chunk). Phase 1: P = tril(qp.kp^T) via 36 16x16 tiles over 8 waves.
// Phase 2: wave w owns t-rows [16w,16w+16): O = P.V (triangular ks<=w>>1) + qp.St^T; denom fused
// via ones/z B-frags. P,Vt stored XOR-swizzled (col^((row&7)<<3), no pad): quarter-wave b128
// reads are 2-way (free). LDS 49.4KB -> 3 blocks/CU x 8 waves = 24 waves/CU (75% cap) for TLP.
__global__ __launch_bounds__(512) void chunk_out(const u16* __restrict__ qp, const u16* __restrict__ kp,
                                                 const u16* __restrict__ vh, const u16* __restrict__ St,
                                                 const float* __restrict__ zs, u16* __restrict__ y2d)
{
    __shared__ u16 P[128][128];
    __shared__ u16 Vt[64][128];
    __shared__ u16 zl[128];
    int blk = blockIdx.x, tid = threadIdx.x;
    int lane = tid & 63, w = tid >> 6;          // 8 waves
    int m = lane & 15, q = lane >> 4;
    int bh = blk >> 4, c = blk & 15;
    int b = bh >> 4, h = bh & 15, t0 = c*128;
    const u16* qpb = qp + ((size_t)bh*2048 + t0)*128;
    const u16* kpb = kp + ((size_t)bh*2048 + t0)*128;
    const u16* vb  = vh + ((size_t)bh*2048 + t0)*64;
    const u16* Stb = St + (size_t)blk*8192;
    const int xm = (m & 7) << 3;                // read-side swizzle (row&7 == m&7 for all reads)

    if (tid < 128) zl[tid] = f2b(zs[(size_t)blk*128 + tid]);
    // stage V transposed (swizzled): Vt[d][t ^ ((d&7)<<3)]
#pragma unroll
    for (int it = 0; it < 2; it++){
        int idx = tid + 512*it;
        int t = idx >> 3, d8 = (idx & 7)*8;
        uint4 v = *reinterpret_cast<const uint4*>(&vb[(size_t)t*64 + d8]);
        u32 ww[4] = {v.x, v.y, v.z, v.w};
#pragma unroll
        for (int j = 0; j < 4; j++){
            Vt[d8 + 2*j]    [t ^ ((2*j)     << 3)] = (u16)(ww[j] & 0xFFFFu);
            Vt[d8 + 2*j + 1][t ^ ((2*j + 1) << 3)] = (u16)(ww[j] >> 16);
        }
    }
    // zero strict-upper P (cols >= 16*(i+1)), swizzled u32 writes
    {
        int row = tid >> 2, c4 = tid & 3;
        int i = row >> 4, xr = (row & 7) << 3;
        for (int s2 = 16*(i + 1) + c4*2; s2 < 128; s2 += 8)
            *reinterpret_cast<u32*>(&P[row][s2 ^ xr]) = 0;
    }
    // phase 1: 36 lower-tri tiles round-robin over 8 waves (5/5/5/5/4/4/4/4)
    {
        static const unsigned char TIa[36] = {0,1,1,2,2,2,3,3,3,3,4,4,4,4,4,
                                              5,5,5,5,5,5,6,6,6,6,6,6,6,7,7,7,7,7,7,7,7};
        static const unsigned char TJa[36] = {0,0,1,0,1,2,0,1,2,3,0,1,2,3,4,
                                              0,1,2,3,4,5,0,1,2,3,4,5,6,0,1,2,3,4,5,6,7};
        for (int idx = w; idx < 36; idx += 8){
            int i = TIa[idx], j = TJa[idx];
            f32x4 a = {};
            const u16* arow = qpb + (size_t)(i*16 + m)*128 + q*8;
            const u16* brow = kpb + (size_t)(j*16 + m)*128 + q*8;
#pragma unroll
            for (int ks = 0; ks < 4; ks++){
                bf16x8 af = LD8(arow + ks*32);
                bf16x8 bf = LD8(brow + ks*32);
                a = __builtin_amdgcn_mfma_f32_16x16x32_bf16(af, bf, a, 0, 0, 0);
            }
            int scol = j*16 + m;
#pragma unroll
            for (int r = 0; r < 4; r++){
                int trow = i*16 + q*4 + r;
                P[trow][scol ^ ((trow & 7) << 3)] = (scol <= trow) ? f2b(a[r]) : (u16)0;
            }
        }
    }
    __syncthreads();
    // phase 2: wave w -> t-rows [16w,16w+16); acc over d=64 (nt 0-3) + fused denominator
    f32x4 acc4[4] = {};
    f32x4 accd = {};
    bf16x8 ones;
#pragma unroll
    for (int i = 0; i < 8; i++) ones[i] = (__bf16)1.0f;
    for (int ks = 0; ks <= (w >> 1); ks++){
        bf16x8 af = LD8(&P[16*w + m][(ks*32 + q*8) ^ xm]);
        bf16x8 bf4[4];
#pragma unroll
        for (int nt = 0; nt < 4; nt++)
            bf4[nt] = LD8(&Vt[nt*16 + m][(ks*32 + q*8) ^ xm]);
#pragma unroll
        for (int nt = 0; nt < 4; nt++)
            acc4[nt] = __builtin_amdgcn_mfma_f32_16x16x32_bf16(af, bf4[nt], acc4[nt], 0, 0, 0);
        accd = __builtin_amdgcn_mfma_f32_16x16x32_bf16(af, ones, accd, 0, 0, 0);
    }
#pragma unroll
    for (int ks = 0; ks < 4; ks++){
        bf16x8 af = LD8(qpb + (size_t)(16*w + m)*128 + ks*32 + q*8);
        bf16x8 zf = LD8(&zl[ks*32 + q*8]);
        bf16x8 bf4[4];
#pragma unroll
        for (int nt = 0; nt < 4; nt++)
            bf4[nt] = LD8(Stb + (size_t)(nt*16 + m)*128 + ks*32 + q*8);
#pragma unroll
        for (int nt = 0; nt < 4; nt++)
            acc4[nt] = __builtin_amdgcn_mfma_f32_16x16x32_bf16(af, bf4[nt], acc4[nt], 0, 0, 0);
        accd = __builtin_amdgcn_mfma_f32_16x16x32_bf16(af, zf, accd, 0, 0, 0);
    }
    // epilogue: t = 16w + q*4 + r, d = nt*16 + m
#pragma unroll
    for (int nt = 0; nt < 4; nt++){
#pragma unroll
        for (int r = 0; r < 4; r++){
            int t = 16*w + q*4 + r;
            int d = nt*16 + m;
            float den = accd[r] + 1e-6f;
            y2d[((size_t)b*2048 + t0 + t)*1024 + h*64 + d] = f2b(acc4[nt][r] / den);
        }
    }
}

extern "C" void kernel_launch(void* const* d_in, const int* in_sizes, int n_in,
                              void* d_out, int out_size, void* d_ws, size_t ws_size,
                              hipStream_t stream)
{
    (void)in_sizes; (void)n_in; (void)out_size; (void)ws_size;
    const float* x  = (const float*)d_in[0];
    const float* Wq = (const float*)d_in[1];
    const float* Wk = (const float*)d_in[2];
    const float* Wv = (const float*)d_in[3];
    const float* Wo = (const float*)d_in[4];
    const float* Wf = (const float*)d_in[5];
    float* out = (float*)d_out;
    char* ws = (char*)d_ws;

    // workspace layout (lifetime-aliased, ~136.5 MiB)
    u16*   xh    = (u16*)  (ws + 0);           // 16MB x bf16 (dead after QKV gemm)
    u16*   Sa    = (u16*)  (ws + 0);           // alias xh: chunk S^T raw bf16
    u16*   qh    = (u16*)  (ws + 16777216);    // 16MB (dead after featmap q)
    u16*   Sbp   = (u16*)  (ws + 16777216);    // alias qh: prefix S^T
    u16*   kh    = (u16*)  (ws + 33554432);    // 16MB (dead after featmap_sum)
    u16*   y2d   = (u16*)  (ws + 33554432);    // alias kh
    u16*   vh    = (u16*)  (ws + 50331648);    // 16MB
    u16*   qp    = (u16*)  (ws + 67108864);    // 32MB
    u16*   kp    = (u16*)  (ws + 100663296);   // 32MB
    u16*   WTqkv = (u16*)  (ws + 134217728);   // 6MB (3 x 1024x1024 bf16)
    u16*   WTo   = (u16*)  (ws + 140509184);   // 2MB
    float* zs    = (float*)(ws + 142606336);   // 0.5MB

    tobf16<<<4096, 256, 0, stream>>>(x, xh);
    transpose_all<<<dim3(16, 16, 4), 256, 0, stream>>>(Wq, Wk, Wv, Wo, WTqkv, WTo);

    // fused QKV: writes qh, kh, vh (contiguous 16MB blocks starting at qh); 768 blocks = 3 exact rounds
    gemm_2p<3><<<dim3(64, 12), 512, 0, stream>>>(xh, WTqkv, nullptr, qh);

    featmap_mfma<<<1024, 256, 0, stream>>>(qh, Wf, qp);
    featmap_sum<<<1024, 256, 0, stream>>>(kh, Wf, vh, kp, Sa, zs);

    prefix_chunks<<<dim3(64, 8), 256, 0, stream>>>(Sa, Sbp, zs);
    chunk_out<<<1024, 512, 0, stream>>>(qp, kp, vh, Sbp, zs, y2d);

    // out-proj: 256 blocks = 1 exact round
    gemm_2p<2><<<dim3(64, 4), 512, 0, stream>>>(y2d, WTo, out, nullptr);
}